// Round 1
// baseline (2746.456 us; speedup 1.0000x reference)
//
#include <hip/hip_runtime.h>

#define NN 100000          // nodes
#define NE 600000          // edges
#define NF 166             // in features
#define NH 128             // hidden
#define NNH 12800000       // NN*NH

enum { EPI_PLAIN = 0, EPI_ACC = 1, EPI_RELU = 2, EPI_H = 3 };

#define BM 64
#define BN 64
#define BK 16

// C[n,m] = epi( sum_k A[n,k]*W[m,k] ), A:[nrows,lda], W:[M,ldw], C:[nrows,ldc]
template<int EPI>
__launch_bounds__(256)
__global__ void gemm_tn(const float* __restrict__ A, int lda,
                        const float* __restrict__ W, int ldw,
                        float* __restrict__ C, int ldc,
                        int nrows, int K, int M,
                        const float* __restrict__ bias,
                        const float* __restrict__ b2v,   // b_time (EPI_H)
                        const float* __restrict__ wtv,   // W_time col (EPI_H)
                        const float* __restrict__ nt,    // node time enc (EPI_H)
                        const float* __restrict__ mem,   // memory (EPI_H)
                        const int* __restrict__ scal)    // tmin/tmax bits (EPI_H)
{
  __shared__ float As[BK][BM + 4];  // stride 68 floats: 16B-aligned rows, 2-way banks (free)
  __shared__ float Bs[BK][BN + 4];
  const int tid = threadIdx.x;
  const int tx = tid & 15, ty = tid >> 4;
  const int row0 = blockIdx.y * BM, col0 = blockIdx.x * BN;
  const int lr = tid >> 2;              // 0..63
  const int lk = (tid & 3) << 2;        // 0,4,8,12
  float acc[4][4] = {};
  for (int k0 = 0; k0 < K; k0 += BK) {
#pragma unroll
    for (int q = 0; q < 4; ++q) {
      int k = k0 + lk + q;
      int gr = row0 + lr;
      int gm = col0 + lr;
      As[lk + q][lr] = (gr < nrows && k < K) ? A[gr * lda + k] : 0.f;
      Bs[lk + q][lr] = (gm < M && k < K) ? W[gm * ldw + k] : 0.f;
    }
    __syncthreads();
#pragma unroll
    for (int k = 0; k < BK; ++k) {
      float a[4], b[4];
#pragma unroll
      for (int i = 0; i < 4; ++i) a[i] = As[k][(ty << 2) + i];
#pragma unroll
      for (int j = 0; j < 4; ++j) b[j] = Bs[k][(tx << 2) + j];
#pragma unroll
      for (int i = 0; i < 4; ++i)
#pragma unroll
        for (int j = 0; j < 4; ++j)
          acc[i][j] = fmaf(a[i], b[j], acc[i][j]);
    }
    __syncthreads();
  }
#pragma unroll
  for (int i = 0; i < 4; ++i) {
    int gr = row0 + (ty << 2) + i;
    if (gr >= nrows) continue;
    float ntn = 0.f;
    if (EPI == EPI_H) {
      float tmin = __int_as_float(scal[5]);
      float tmax = __int_as_float(scal[6]);
      ntn = nt[gr];
      if (tmax > tmin) ntn = (ntn - tmin) / (tmax - tmin + 1e-8f);
    }
#pragma unroll
    for (int j = 0; j < 4; ++j) {
      int gm = col0 + (tx << 2) + j;
      if (gm >= M) continue;
      float v = acc[i][j];
      if (bias) v += bias[gm];
      if (EPI == EPI_RELU) v = fmaxf(v, 0.f);
      if (EPI == EPI_H) {
        v += ntn * wtv[gm] + b2v[gm];
        v = fmaxf(v, 0.f);
        v += mem[gr * NH + gm];
      }
      if (EPI == EPI_ACC) C[gr * ldc + gm] += v;
      else                C[gr * ldc + gm] = v;
    }
  }
}

// edge pass 1: nt=segment_max(ts,col) via int atomicMax (ts>=0), upd mask,
// in-degree count, 16-bit-high histogram for median selection
__global__ void edge_pass1(const int* __restrict__ row, const int* __restrict__ col,
                           const float* __restrict__ ts,
                           float* __restrict__ nt, int* __restrict__ upd,
                           int* __restrict__ cnt_all, int* __restrict__ hist1)
{
  int e = blockIdx.x * 256 + threadIdx.x;
  if (e >= NE) return;
  int r = row[e], c = col[e];
  float t = ts[e];
  atomicMax((int*)(nt + c), __float_as_int(t));
  upd[r] = 1; upd[c] = 1;
  atomicAdd(cnt_all + c, 1);
  atomicAdd(hist1 + (int)(__float_as_uint(t) >> 16), 1);
}

__global__ void node_minmax(const float* __restrict__ nt, int* __restrict__ scal)
{
  int i = blockIdx.x * 256 + threadIdx.x;
  float v = (i < NN) ? nt[i] : nt[0];   // duplicate of nt[0] is a safe neutral
  float vmin = v, vmax = v;
#pragma unroll
  for (int d = 1; d < 64; d <<= 1) {
    vmin = fminf(vmin, __shfl_xor(vmin, d));
    vmax = fmaxf(vmax, __shfl_xor(vmax, d));
  }
  __shared__ float smin[4], smax[4];
  int lane = threadIdx.x & 63, w = threadIdx.x >> 6;
  if (lane == 0) { smin[w] = vmin; smax[w] = vmax; }
  __syncthreads();
  if (threadIdx.x == 0) {
    float a = fminf(fminf(smin[0], smin[1]), fminf(smin[2], smin[3]));
    float b = fmaxf(fmaxf(smax[0], smax[1]), fmaxf(smax[2], smax[3]));
    atomicMin(scal + 5, __float_as_int(a));  // positive-float bits: int order == float order
    atomicMax(scal + 6, __float_as_int(b));
  }
}

// find buckets of order statistics K1=299999, K2=300000 (0-based) in hist1
__global__ void scan_hist1(const int* __restrict__ hist, int* __restrict__ scal)
{
  const int K1 = 299999, K2 = 300000;
  __shared__ int sums[256];
  __shared__ int pre[257];
  int t = threadIdx.x;
  int s = 0;
  for (int i = 0; i < 256; ++i) s += hist[t * 256 + i];
  sums[t] = s;
  __syncthreads();
  if (t == 0) { int run = 0; for (int i = 0; i < 256; ++i) { pre[i] = run; run += sums[i]; } pre[256] = run; }
  __syncthreads();
  int base = pre[t], nexts = base + sums[t];
  if (K1 >= base && K1 < nexts) {
    int run = base;
    for (int i = 0; i < 256; ++i) {
      int cv = hist[t * 256 + i];
      if (K1 < run + cv) { scal[0] = t * 256 + i; scal[1] = run; break; }
      run += cv;
    }
  }
  if (K2 >= base && K2 < nexts) {
    int run = base;
    for (int i = 0; i < 256; ++i) {
      int cv = hist[t * 256 + i];
      if (K2 < run + cv) { scal[2] = t * 256 + i; scal[3] = run; break; }
      run += cv;
    }
  }
}

__global__ void edge_hist2(const float* __restrict__ ts, const int* __restrict__ scal,
                           int* __restrict__ h2a, int* __restrict__ h2b)
{
  int e = blockIdx.x * 256 + threadIdx.x;
  if (e >= NE) return;
  unsigned u = __float_as_uint(ts[e]);
  int hb = (int)(u >> 16);
  if (hb == scal[0]) atomicAdd(h2a + (u & 0xffff), 1);
  if (hb == scal[2]) atomicAdd(h2b + (u & 0xffff), 1);
}

// resolve low 16 bits of both order statistics; med = mean of the two (exact jnp.median)
__global__ void scan_hist2(const int* __restrict__ ha, const int* __restrict__ hb,
                           int* __restrict__ scal)
{
  __shared__ int sums[256];
  __shared__ int pre[257];
  __shared__ unsigned res[2];
  int t = threadIdx.x;
  for (int which = 0; which < 2; ++which) {
    const int* h = which ? hb : ha;
    int rank = which ? (300000 - scal[3]) : (299999 - scal[1]);
    int s = 0;
    for (int i = 0; i < 256; ++i) s += h[t * 256 + i];
    sums[t] = s;
    __syncthreads();
    if (t == 0) { int run = 0; for (int i = 0; i < 256; ++i) { pre[i] = run; run += sums[i]; } pre[256] = run; }
    __syncthreads();
    int base = pre[t], nexts = base + sums[t];
    if (rank >= base && rank < nexts) {
      int run = base;
      for (int i = 0; i < 256; ++i) {
        int cv = h[t * 256 + i];
        if (rank < run + cv) { res[which] = (unsigned)(t * 256 + i); break; }
        run += cv;
      }
    }
    __syncthreads();
  }
  if (t == 0) {
    unsigned v1 = ((unsigned)scal[0] << 16) | res[0];
    unsigned v2 = ((unsigned)scal[2] << 16) | res[1];
    float med = 0.5f * (__uint_as_float(v1) + __uint_as_float(v2));
    ((float*)scal)[4] = med;
  }
}

__global__ void edge_cntrec(const int* __restrict__ col, const float* __restrict__ ts,
                            const int* __restrict__ scal, int* __restrict__ cnt_rec)
{
  int e = blockIdx.x * 256 + threadIdx.x;
  if (e >= NE) return;
  float med = __int_as_float(scal[4]);
  if (ts[e] >= med) atomicAdd(cnt_rec + col[e], 1);
}

__global__ void node_dis(const int* __restrict__ cnt_all, const int* __restrict__ cnt_rec,
                         float* __restrict__ dr, float* __restrict__ dh)
{
  int n = blockIdx.x * 256 + threadIdx.x;
  if (n >= NN) return;
  int ca = cnt_all[n], cr = cnt_rec[n];
  dr[n] = rsqrtf((float)cr + 1.f);
  dh[n] = rsqrtf((float)(ca - cr) + 1.f);
}

// P[n,0:128]=r-gate preact sum, P[n,128:256]=z-gate preact sum, P[n,256:384]=ic, Q[n,:]=hc
__global__ void gru_kernel(const float* __restrict__ P, const float* __restrict__ Q,
                           const float* __restrict__ mem, const int* __restrict__ upd,
                           float* __restrict__ out)
{
  int idx = blockIdx.x * 256 + threadIdx.x;
  if (idx >= NNH) return;
  int n = idx >> 7, m = idx & 127;
  float mv = mem[idx];
  float o = mv;
  if (upd[n]) {
    int base = n * 384;
    float r = 1.f / (1.f + expf(-P[base + m]));
    float z = 1.f / (1.f + expf(-P[base + 128 + m]));
    float c = tanhf(P[base + 256 + m] + r * Q[idx]);
    o = (1.f - z) * c + z * mv;
  }
  out[idx] = o;
}

// one 64-lane wave per edge; float2 per lane; skip edges of the other path
__global__ void scatter_edges(const int* __restrict__ row, const int* __restrict__ col,
                              const float* __restrict__ ts, const int* __restrict__ scal,
                              const float* __restrict__ dis,
                              const float* __restrict__ hl, float* __restrict__ agg,
                              int want_rec)
{
  int e = blockIdx.x * 4 + (threadIdx.x >> 6);
  if (e >= NE) return;
  int lane = threadIdx.x & 63;
  float med = __int_as_float(scal[4]);
  int rec = (ts[e] >= med) ? 1 : 0;
  if (rec != want_rec) return;
  int r = row[e], c = col[e];
  float coef = dis[r] * dis[c];
  const float2 v = *(const float2*)(hl + r * NH + (lane << 1));
  atomicAdd(agg + c * NH + (lane << 1),     v.x * coef);
  atomicAdd(agg + c * NH + (lane << 1) + 1, v.y * coef);
}

__global__ void selfloop_bias(float* __restrict__ agg, const float* __restrict__ hl,
                              const float* __restrict__ dis, const float* __restrict__ b)
{
  int idx = blockIdx.x * 256 + threadIdx.x;
  if (idx >= NNH) return;
  int n = idx >> 7, m = idx & 127;
  float d = dis[n];
  agg[idx] += hl[idx] * d * d + b[m];
}

// softmax over per-path means, weighted sum, LayerNorm -> out
__global__ void combine_pa(const float* __restrict__ hr, const float* __restrict__ hh,
                           const float* __restrict__ g, const float* __restrict__ b,
                           float* __restrict__ out)
{
  int n = blockIdx.x * 4 + (threadIdx.x >> 6);
  if (n >= NN) return;
  int lane = threadIdx.x & 63;
  int off = n * NH + (lane << 1);
  float2 a = *(const float2*)(hr + off);
  float2 c = *(const float2*)(hh + off);
  float sa = a.x + a.y, sc = c.x + c.y;
#pragma unroll
  for (int d = 1; d < 64; d <<= 1) { sa += __shfl_xor(sa, d); sc += __shfl_xor(sc, d); }
  float m0 = sa * (1.f / 128.f), m1 = sc * (1.f / 128.f);
  float mx = fmaxf(m0, m1);
  float e0 = expf(m0 - mx), e1 = expf(m1 - mx);
  float inv = 1.f / (e0 + e1);
  float w0 = e0 * inv, w1 = e1 * inv;
  float yx = w0 * a.x + w1 * c.x;
  float yy = w0 * a.y + w1 * c.y;
  float s = yx + yy;
#pragma unroll
  for (int d = 1; d < 64; d <<= 1) s += __shfl_xor(s, d);
  float mean = s * (1.f / 128.f);
  float dx = yx - mean, dy = yy - mean;
  float vv = dx * dx + dy * dy;
#pragma unroll
  for (int d = 1; d < 64; d <<= 1) vv += __shfl_xor(vv, d);
  float rstd = rsqrtf(vv * (1.f / 128.f) + 1e-5f);
  float2 gg = *(const float2*)(g + (lane << 1));
  float2 bb = *(const float2*)(b + (lane << 1));
  float2 o;
  o.x = dx * rstd * gg.x + bb.x;
  o.y = dy * rstd * gg.y + bb.y;
  *(float2*)(out + off) = o;
}

// out = LN(x + y)
__global__ void ln_residual(const float* __restrict__ x, const float* __restrict__ y,
                            const float* __restrict__ g, const float* __restrict__ b,
                            float* __restrict__ out)
{
  int n = blockIdx.x * 4 + (threadIdx.x >> 6);
  if (n >= NN) return;
  int lane = threadIdx.x & 63;
  int off = n * NH + (lane << 1);
  float2 xv = *(const float2*)(x + off);
  float2 yv = *(const float2*)(y + off);
  float ax = xv.x + yv.x, ay = xv.y + yv.y;
  float s = ax + ay;
#pragma unroll
  for (int d = 1; d < 64; d <<= 1) s += __shfl_xor(s, d);
  float mean = s * (1.f / 128.f);
  float dx = ax - mean, dy = ay - mean;
  float vv = dx * dx + dy * dy;
#pragma unroll
  for (int d = 1; d < 64; d <<= 1) vv += __shfl_xor(vv, d);
  float rstd = rsqrtf(vv * (1.f / 128.f) + 1e-5f);
  float2 gg = *(const float2*)(g + (lane << 1));
  float2 bb = *(const float2*)(b + (lane << 1));
  float2 o;
  o.x = dx * rstd * gg.x + bb.x;
  o.y = dy * rstd * gg.y + bb.y;
  *(float2*)(out + off) = o;
}

// logits = R @ W2.T + b2, M=2, K=64
__global__ void head_kernel(const float* __restrict__ R, const float* __restrict__ W2,
                            const float* __restrict__ b2, float* __restrict__ out)
{
  int n = blockIdx.x * 256 + threadIdx.x;
  if (n >= NN) return;
  const float* rr = R + n * 64;
  float a0 = 0.f, a1 = 0.f;
#pragma unroll
  for (int k = 0; k < 64; ++k) {
    float v = rr[k];
    a0 = fmaf(v, W2[k], a0);
    a1 = fmaf(v, W2[64 + k], a1);
  }
  out[n * 2]     = a0 + b2[0];
  out[n * 2 + 1] = a1 + b2[1];
}

extern "C" void kernel_launch(void* const* d_in, const int* in_sizes, int n_in,
                              void* d_out, int out_size, void* d_ws, size_t ws_size,
                              hipStream_t stream)
{
  const float* x      = (const float*)d_in[0];
  const int*   ei     = (const int*)  d_in[1];
  const float* ts     = (const float*)d_in[2];
  const float* mem    = (const float*)d_in[3];
  const float* W_in   = (const float*)d_in[4];
  const float* b_in   = (const float*)d_in[5];
  const float* W_time = (const float*)d_in[6];
  const float* b_time = (const float*)d_in[7];
  const float* W_ih   = (const float*)d_in[8];
  const float* W_hh   = (const float*)d_in[9];
  const float* b_ih   = (const float*)d_in[10];
  const float* b_hh   = (const float*)d_in[11];
  const float* W_gr   = (const float*)d_in[12];
  const float* b_gr   = (const float*)d_in[13];
  const float* W_gh   = (const float*)d_in[14];
  const float* b_gh   = (const float*)d_in[15];
  const float* ln_pa_g= (const float*)d_in[16];
  const float* ln_pa_b= (const float*)d_in[17];
  const float* Wv     = (const float*)d_in[18];
  const float* bv     = (const float*)d_in[19];
  const float* Wo     = (const float*)d_in[20];
  const float* bo     = (const float*)d_in[21];
  const float* ln_at_g= (const float*)d_in[22];
  const float* ln_at_b= (const float*)d_in[23];
  const float* W1     = (const float*)d_in[24];
  const float* b1     = (const float*)d_in[25];
  const float* W2     = (const float*)d_in[26];
  const float* b2     = (const float*)d_in[27];

  const int* row = ei;
  const int* col = ei + NE;

  float* out_logits = (float*)d_out;          // [NN,2]
  float* out_mem    = (float*)d_out + NN * 2; // [NN,128]

  // workspace layout (floats) — total ~259.2 MB
  float* ws      = (float*)d_ws;
  float* h       = ws;                  // 12.8M
  float* pool    = ws + 12800000;       // 51.2M, phase-reused
  float* P       = pool;                // gi/sums  [NN,384]
  float* Q       = pool + 38400000;     // hc       [NN,128]
  float* bufA    = pool;                // hl / vtmp / relu1
  float* bufB    = pool + 12800000;     // agg_rec / att
  float* bufC    = pool + 25600000;     // agg_his / h_at
  float* nt      = ws + 64000000;
  float* dis_rec = ws + 64100000;
  float* dis_his = ws + 64200000;
  int* cnt_all = (int*)(ws + 64300000);
  int* cnt_rec = (int*)(ws + 64400000);
  int* upd     = (int*)(ws + 64500000);
  int* hist1   = (int*)(ws + 64600000);
  int* h2a     = (int*)(ws + 64665536);
  int* h2b     = (int*)(ws + 64731072);
  int* scal    = (int*)(ws + 64796608); // [0]b1 [1]c1 [2]b2 [3]c2 [4]med [5]tminbits [6]tmaxbits

  hipMemsetAsync(nt,      0, NN * 4, stream);
  hipMemsetAsync(cnt_all, 0, NN * 4, stream);
  hipMemsetAsync(cnt_rec, 0, NN * 4, stream);
  hipMemsetAsync(upd,     0, NN * 4, stream);
  hipMemsetAsync(hist1,   0, 65536 * 4, stream);
  hipMemsetAsync(h2a,     0, 65536 * 4, stream);
  hipMemsetAsync(h2b,     0, 65536 * 4, stream);
  hipMemsetAsync(scal,    0, 16 * 4, stream);
  hipMemsetAsync(scal + 5, 0x7f, 4, stream);  // tmin init = huge positive float bits

  const int eb = (NE + 255) / 256;
  const int nb = (NN + 255) / 256;
  const int nhb = (NNH + 255) / 256;

  edge_pass1 <<<eb, 256, 0, stream>>>(row, col, ts, nt, upd, cnt_all, hist1);
  node_minmax<<<nb, 256, 0, stream>>>(nt, scal);
  scan_hist1 <<<1, 256, 0, stream>>>(hist1, scal);
  edge_hist2 <<<eb, 256, 0, stream>>>(ts, scal, h2a, h2b);
  scan_hist2 <<<1, 256, 0, stream>>>(h2a, h2b, scal);
  edge_cntrec<<<eb, 256, 0, stream>>>(col, ts, scal, cnt_rec);
  node_dis   <<<nb, 256, 0, stream>>>(cnt_all, cnt_rec, dis_rec, dis_his);

  dim3 blk(256);
  auto gg = [](int M) { return dim3((unsigned)((M + BN - 1) / BN), (unsigned)((NN + BM - 1) / BM)); };

  // h = relu(x@W_in.T + b_in + nt*W_time + b_time) + memory
  gemm_tn<EPI_H><<<gg(128), blk, 0, stream>>>(x, NF, W_in, NF, h, NH, NN, NF, 128,
      b_in, b_time, W_time, nt, mem, scal);
  // P = h@W_ih.T + b_ih   [NN,384]
  gemm_tn<EPI_PLAIN><<<gg(384), blk, 0, stream>>>(h, NH, W_ih, NH, P, 384, NN, NH, 384,
      b_ih, nullptr, nullptr, nullptr, nullptr, nullptr);
  // P[:, :256] += mem@W_hh[:256].T + b_hh[:256]   (r,z gate sums)
  gemm_tn<EPI_ACC><<<gg(256), blk, 0, stream>>>(mem, NH, W_hh, NH, P, 384, NN, NH, 256,
      b_hh, nullptr, nullptr, nullptr, nullptr, nullptr);
  // Q = mem@W_hh[256:].T + b_hh[256:]   (hc)
  gemm_tn<EPI_PLAIN><<<gg(128), blk, 0, stream>>>(mem, NH, W_hh + 256 * NH, NH, Q, NH, NN, NH, 128,
      b_hh + 256, nullptr, nullptr, nullptr, nullptr, nullptr);
  gru_kernel<<<nhb, 256, 0, stream>>>(P, Q, mem, upd, out_mem);

  // GCN recent path
  gemm_tn<EPI_PLAIN><<<gg(128), blk, 0, stream>>>(h, NH, W_gr, NH, bufA, NH, NN, NH, 128,
      nullptr, nullptr, nullptr, nullptr, nullptr, nullptr);
  hipMemsetAsync(bufB, 0, (size_t)NNH * 4, stream);
  scatter_edges<<<(NE + 3) / 4, 256, 0, stream>>>(row, col, ts, scal, dis_rec, bufA, bufB, 1);
  selfloop_bias<<<nhb, 256, 0, stream>>>(bufB, bufA, dis_rec, b_gr);
  // GCN history path
  gemm_tn<EPI_PLAIN><<<gg(128), blk, 0, stream>>>(h, NH, W_gh, NH, bufA, NH, NN, NH, 128,
      nullptr, nullptr, nullptr, nullptr, nullptr, nullptr);
  hipMemsetAsync(bufC, 0, (size_t)NNH * 4, stream);
  scatter_edges<<<(NE + 3) / 4, 256, 0, stream>>>(row, col, ts, scal, dis_his, bufA, bufC, 0);
  selfloop_bias<<<nhb, 256, 0, stream>>>(bufC, bufA, dis_his, b_gh);

  // path aggregation + LN  -> h (overwrite; old h dead)
  combine_pa<<<(NN + 3) / 4, 256, 0, stream>>>(bufB, bufC, ln_pa_g, ln_pa_b, h);

  // attention (query path cancels): att = (h@Wv.T+bv)@Wo.T+bo ; h = LN(h+att)
  gemm_tn<EPI_PLAIN><<<gg(128), blk, 0, stream>>>(h, NH, Wv, NH, bufA, NH, NN, NH, 128,
      bv, nullptr, nullptr, nullptr, nullptr, nullptr);
  gemm_tn<EPI_PLAIN><<<gg(128), blk, 0, stream>>>(bufA, NH, Wo, NH, bufB, NH, NN, NH, 128,
      bo, nullptr, nullptr, nullptr, nullptr, nullptr);
  ln_residual<<<(NN + 3) / 4, 256, 0, stream>>>(h, bufB, ln_at_g, ln_at_b, bufC);

  // classifier
  gemm_tn<EPI_RELU><<<gg(64), blk, 0, stream>>>(bufC, NH, W1, NH, bufA, 64, NN, NH, 64,
      b1, nullptr, nullptr, nullptr, nullptr, nullptr);
  head_kernel<<<nb, 256, 0, stream>>>(bufA, W2, b2, out_logits);

  (void)in_sizes; (void)n_in; (void)out_size; (void)ws_size;
}

// Round 2
// 1784.115 us; speedup vs baseline: 1.5394x; 1.5394x over previous
//
#include <hip/hip_runtime.h>

#define NN 100000
#define NE 600000
#define NF 166
#define NH 128
#define NNH 12800000

enum { EPI_PLAIN = 0, EPI_ACC = 1, EPI_RELU = 2, EPI_H = 3 };

typedef short bf16x8 __attribute__((ext_vector_type(8)));
typedef float f32x16 __attribute__((ext_vector_type(16)));

__device__ __forceinline__ unsigned short f2bf(float f) {
  unsigned u = __float_as_uint(f);
  u += 0x7fffu + ((u >> 16) & 1u);
  return (unsigned short)(u >> 16);
}

// ---------------- MFMA GEMM: C[n,m] = epi(sum_k A[n,k]*W[m,k]) -------------
// A: bf16 [NN, lda], W: bf16 [M, ldw], tile 128x128, BK=64, 4 waves.
// LDS: unpadded 128B rows, 16B-chunk XOR swizzle (slot = chunk ^ (row&7)) ->
// conflict-free ds_read_b128 fragments AND contiguous staging.
template<int EPI, bool WF32, bool WB16>
__launch_bounds__(256)
__global__ void mgemm(const unsigned short* __restrict__ A, int lda,
                      const unsigned short* __restrict__ W, int ldw,
                      float* C, int ldc,
                      unsigned short* Cb, int ldcb,
                      int K, int M,
                      const float* __restrict__ bias,
                      const float* __restrict__ b2v,   // b_time (EPI_H)
                      const float* __restrict__ wtv,   // W_time col (EPI_H)
                      const float* __restrict__ nt,    // node time enc (EPI_H)
                      const float* __restrict__ mem,   // memory (EPI_H)
                      const int* __restrict__ scal)
{
  __shared__ unsigned short As[128 * 64];
  __shared__ unsigned short Bs[128 * 64];
  const int tid = threadIdx.x;
  const int wave = tid >> 6, lane = tid & 63;
  const int row0 = blockIdx.y * 128, col0 = blockIdx.x * 128;
  const int hi = lane >> 5, l5 = lane & 31, l3 = lane & 7;
  f32x16 acc[4] = {};

  for (int k0 = 0; k0 < K; k0 += 64) {
    __syncthreads();
#pragma unroll
    for (int q = 0; q < 4; ++q) {
      int id = q * 256 + tid;
      int r = id >> 3, cch = id & 7;
      int slot8 = ((cch ^ (r & 7)) << 3);
      int gr = row0 + r; if (gr > NN - 1) gr = NN - 1;
      *(int4*)&As[r * 64 + slot8] = *(const int4*)(A + (size_t)gr * lda + k0 + cch * 8);
      int gm = col0 + r; if (gm > M - 1) gm = M - 1;
      *(int4*)&Bs[r * 64 + slot8] = *(const int4*)(W + (size_t)gm * ldw + k0 + cch * 8);
    }
    __syncthreads();
#pragma unroll
    for (int s = 0; s < 4; ++s) {
      int slot8 = (((s * 2 + hi) ^ l3) << 3);
      bf16x8 a = *(const bf16x8*)&As[(wave * 32 + l5) * 64 + slot8];
#pragma unroll
      for (int t = 0; t < 4; ++t) {
        bf16x8 b = *(const bf16x8*)&Bs[(t * 32 + l5) * 64 + slot8];
        acc[t] = __builtin_amdgcn_mfma_f32_32x32x16_bf16(a, b, acc[t], 0, 0, 0);
      }
    }
  }

  float tmin = 0.f, tmax = 0.f;
  if (EPI == EPI_H) { tmin = __int_as_float(scal[5]); tmax = __int_as_float(scal[6]); }
#pragma unroll
  for (int rg = 0; rg < 16; ++rg) {
    int lr = (rg & 3) + 8 * (rg >> 2) + 4 * hi;
    int grow = row0 + wave * 32 + lr;
    if (grow >= NN) continue;
    float ntn = 0.f;
    if (EPI == EPI_H) {
      ntn = nt[grow];
      if (tmax > tmin) ntn = (ntn - tmin) / (tmax - tmin + 1e-8f);
    }
#pragma unroll
    for (int t = 0; t < 4; ++t) {
      int gcol = col0 + t * 32 + l5;
      if (gcol >= M) continue;
      float v = acc[t][rg];
      if (bias) v += bias[gcol];
      if (EPI == EPI_RELU) v = fmaxf(v, 0.f);
      if (EPI == EPI_H) {
        v += ntn * wtv[gcol] + b2v[gcol];
        v = fmaxf(v, 0.f);
        v += mem[(size_t)grow * NH + gcol];
      }
      if (EPI == EPI_ACC) v += C[(size_t)grow * ldc + gcol];
      if (WF32) C[(size_t)grow * ldc + gcol] = v;
      if (WB16) Cb[(size_t)grow * ldcb + gcol] = f2bf(v);
    }
  }
}

// ---------------- pre-convert kernels --------------------------------------
__global__ void conv_x(const float* __restrict__ x, unsigned short* __restrict__ xb)
{
  int i = blockIdx.x * 256 + threadIdx.x;
  if (i >= NN * 192) return;
  int n = i / 192, c = i - n * 192;
  xb[i] = (c < NF) ? f2bf(x[n * NF + c]) : (unsigned short)0;
}

__global__ void conv_mem(const float* __restrict__ m, unsigned short* __restrict__ mb)
{
  int i = blockIdx.x * 256 + threadIdx.x;
  if (i >= NNH) return;
  mb[i] = f2bf(m[i]);
}

__global__ void conv_w(const float* __restrict__ Wi, const float* __restrict__ Wih,
                       const float* __restrict__ Whh, const float* __restrict__ Wgr,
                       const float* __restrict__ Wgh, const float* __restrict__ Wv,
                       const float* __restrict__ Wo, const float* __restrict__ W1,
                       unsigned short* __restrict__ wb)
{
  int i = blockIdx.x * 256 + threadIdx.x;
  if (i >= 196608) return;
  float v;
  if (i < 24576)       { int r = i / 192, c = i - r * 192; v = (c < NF) ? Wi[r * NF + c] : 0.f; }
  else if (i < 73728)  v = Wih[i - 24576];
  else if (i < 122880) v = Whh[i - 73728];
  else if (i < 139264) v = Wgr[i - 122880];
  else if (i < 155648) v = Wgh[i - 139264];
  else if (i < 172032) v = Wv[i - 155648];
  else if (i < 188416) v = Wo[i - 172032];
  else                 v = W1[i - 188416];
  wb[i] = f2bf(v);
}

// ---------------- edge statistics ------------------------------------------
__global__ void edge_pass1(const int* __restrict__ row, const int* __restrict__ col,
                           const float* __restrict__ ts,
                           float* nt, int* upd, int* cnt_all, int* hist1)
{
  int e = blockIdx.x * 256 + threadIdx.x;
  if (e >= NE) return;
  int r = row[e], c = col[e];
  float t = ts[e];
  atomicMax((int*)(nt + c), __float_as_int(t));
  upd[r] = 1; upd[c] = 1;
  atomicAdd(cnt_all + c, 1);
  atomicAdd(hist1 + (int)(__float_as_uint(t) >> 16), 1);
}

__global__ void node_minmax(const float* __restrict__ nt, int* scal)
{
  int i = blockIdx.x * 256 + threadIdx.x;
  float v = (i < NN) ? nt[i] : nt[0];
  float vmin = v, vmax = v;
#pragma unroll
  for (int d = 1; d < 64; d <<= 1) {
    vmin = fminf(vmin, __shfl_xor(vmin, d));
    vmax = fmaxf(vmax, __shfl_xor(vmax, d));
  }
  __shared__ float smin[4], smax[4];
  int lane = threadIdx.x & 63, w = threadIdx.x >> 6;
  if (lane == 0) { smin[w] = vmin; smax[w] = vmax; }
  __syncthreads();
  if (threadIdx.x == 0) {
    float a = fminf(fminf(smin[0], smin[1]), fminf(smin[2], smin[3]));
    float b = fmaxf(fmaxf(smax[0], smax[1]), fmaxf(smax[2], smax[3]));
    atomicMin(scal + 5, __float_as_int(a));
    atomicMax(scal + 6, __float_as_int(b));
  }
}

__global__ void scan_hist1(const int* __restrict__ hist, int* scal)
{
  const int K1 = 299999, K2 = 300000;
  __shared__ int sums[256];
  __shared__ int pre[257];
  int t = threadIdx.x;
  int s = 0;
  for (int i = 0; i < 256; ++i) s += hist[t * 256 + i];
  sums[t] = s;
  __syncthreads();
  if (t == 0) { int run = 0; for (int i = 0; i < 256; ++i) { pre[i] = run; run += sums[i]; } pre[256] = run; }
  __syncthreads();
  int base = pre[t], nexts = base + sums[t];
  if (K1 >= base && K1 < nexts) {
    int run = base;
    for (int i = 0; i < 256; ++i) {
      int cv = hist[t * 256 + i];
      if (K1 < run + cv) { scal[0] = t * 256 + i; scal[1] = run; break; }
      run += cv;
    }
  }
  if (K2 >= base && K2 < nexts) {
    int run = base;
    for (int i = 0; i < 256; ++i) {
      int cv = hist[t * 256 + i];
      if (K2 < run + cv) { scal[2] = t * 256 + i; scal[3] = run; break; }
      run += cv;
    }
  }
}

__global__ void edge_hist2(const float* __restrict__ ts, const int* __restrict__ scal,
                           int* h2a, int* h2b)
{
  int e = blockIdx.x * 256 + threadIdx.x;
  if (e >= NE) return;
  unsigned u = __float_as_uint(ts[e]);
  int hb = (int)(u >> 16);
  if (hb == scal[0]) atomicAdd(h2a + (u & 0xffff), 1);
  if (hb == scal[2]) atomicAdd(h2b + (u & 0xffff), 1);
}

__global__ void scan_hist2(const int* __restrict__ ha, const int* __restrict__ hb,
                           int* scal)
{
  __shared__ int sums[256];
  __shared__ int pre[257];
  __shared__ unsigned res[2];
  int t = threadIdx.x;
  for (int which = 0; which < 2; ++which) {
    const int* h = which ? hb : ha;
    int rank = which ? (300000 - scal[3]) : (299999 - scal[1]);
    int s = 0;
    for (int i = 0; i < 256; ++i) s += h[t * 256 + i];
    sums[t] = s;
    __syncthreads();
    if (t == 0) { int run = 0; for (int i = 0; i < 256; ++i) { pre[i] = run; run += sums[i]; } pre[256] = run; }
    __syncthreads();
    int base = pre[t], nexts = base + sums[t];
    if (rank >= base && rank < nexts) {
      int run = base;
      for (int i = 0; i < 256; ++i) {
        int cv = h[t * 256 + i];
        if (rank < run + cv) { res[which] = (unsigned)(t * 256 + i); break; }
        run += cv;
      }
    }
    __syncthreads();
  }
  if (t == 0) {
    unsigned v1 = ((unsigned)scal[0] << 16) | res[0];
    unsigned v2 = ((unsigned)scal[2] << 16) | res[1];
    ((float*)scal)[4] = 0.5f * (__uint_as_float(v1) + __uint_as_float(v2));
  }
}

__global__ void edge_cntrec(const int* __restrict__ col, const float* __restrict__ ts,
                            const int* __restrict__ scal, int* cnt_rec)
{
  int e = blockIdx.x * 256 + threadIdx.x;
  if (e >= NE) return;
  if (ts[e] >= __int_as_float(scal[4])) atomicAdd(cnt_rec + col[e], 1);
}

__global__ void node_dis(const int* __restrict__ cnt_all, const int* __restrict__ cnt_rec,
                         float* dr, float* dh)
{
  int n = blockIdx.x * 256 + threadIdx.x;
  if (n >= NN) return;
  int ca = cnt_all[n], cr = cnt_rec[n];
  dr[n] = rsqrtf((float)cr + 1.f);
  dh[n] = rsqrtf((float)(ca - cr) + 1.f);
}

// ---------------- GRU ------------------------------------------------------
// P[n,0:256] = gi+gh preact (r,z); P[n,256:384] = ic; Q[n,:] = hc
__global__ void gru_kernel(const float* __restrict__ P, const float* __restrict__ Q,
                           const float* __restrict__ mem, const int* __restrict__ upd,
                           float* out)
{
  int idx = blockIdx.x * 256 + threadIdx.x;
  if (idx >= NNH) return;
  int n = idx >> 7, m = idx & 127;
  float mv = mem[idx];
  float o = mv;
  if (upd[n]) {
    int base = n * 384;
    float r = 1.f / (1.f + expf(-P[base + m]));
    float z = 1.f / (1.f + expf(-P[base + 128 + m]));
    float c = tanhf(P[base + 256 + m] + r * Q[idx]);
    o = (1.f - z) * c + z * mv;
  }
  out[idx] = o;
}

// ---------------- single-pass GCN scatter ----------------------------------
__global__ void scatter_edges(const int* __restrict__ row, const int* __restrict__ col,
                              const float* __restrict__ ts, const int* __restrict__ scal,
                              const float* __restrict__ dis_r, const float* __restrict__ dis_h,
                              const float* __restrict__ hlr, const float* __restrict__ hlh,
                              float* aggB, float* aggC)
{
  int e = blockIdx.x * 4 + (threadIdx.x >> 6);
  if (e >= NE) return;
  int lane = threadIdx.x & 63;
  int rec = (ts[e] >= __int_as_float(scal[4])) ? 1 : 0;
  int r = row[e], c = col[e];
  const float* dis = rec ? dis_r : dis_h;
  const float* hl  = rec ? hlr : hlh;
  float* agg       = rec ? aggB : aggC;
  float coef = dis[r] * dis[c];
  const float2 v = *(const float2*)(hl + (size_t)r * NH + (lane << 1));
  atomicAdd(agg + (size_t)c * NH + (lane << 1),     v.x * coef);
  atomicAdd(agg + (size_t)c * NH + (lane << 1) + 1, v.y * coef);
}

// ---------------- fused self-loop + path softmax + LN ----------------------
// In-place: h2 overwrites aggB. h2b (bf16) -> separate buffer.
__global__ void combine_pa(float* aggB, const float* __restrict__ aggC,
                           const float* __restrict__ hlr, const float* __restrict__ hlh,
                           const float* __restrict__ dis_r, const float* __restrict__ dis_h,
                           const float* __restrict__ bgr, const float* __restrict__ bgh,
                           const float* __restrict__ g, const float* __restrict__ b,
                           unsigned short* h2b)
{
  int n = blockIdx.x * 4 + (threadIdx.x >> 6);
  if (n >= NN) return;
  int lane = threadIdx.x & 63;
  int off = n * NH + (lane << 1);
  float dr = dis_r[n], dh = dis_h[n];
  float2 aB = *(const float2*)(aggB + off);
  float2 aC = *(const float2*)(aggC + off);
  float2 lr = *(const float2*)(hlr + off);
  float2 lh = *(const float2*)(hlh + off);
  float2 br = *(const float2*)(bgr + (lane << 1));
  float2 bh = *(const float2*)(bgh + (lane << 1));
  float rx = aB.x + lr.x * dr * dr + br.x;
  float ry = aB.y + lr.y * dr * dr + br.y;
  float hx = aC.x + lh.x * dh * dh + bh.x;
  float hy = aC.y + lh.y * dh * dh + bh.y;
  float sa = rx + ry, sc = hx + hy;
#pragma unroll
  for (int d = 1; d < 64; d <<= 1) { sa += __shfl_xor(sa, d); sc += __shfl_xor(sc, d); }
  float m0 = sa * (1.f / 128.f), m1 = sc * (1.f / 128.f);
  float mx = fmaxf(m0, m1);
  float e0 = expf(m0 - mx), e1 = expf(m1 - mx);
  float inv = 1.f / (e0 + e1);
  float w0 = e0 * inv, w1 = e1 * inv;
  float yx = w0 * rx + w1 * hx;
  float yy = w0 * ry + w1 * hy;
  float s = yx + yy;
#pragma unroll
  for (int d = 1; d < 64; d <<= 1) s += __shfl_xor(s, d);
  float mean = s * (1.f / 128.f);
  float dx = yx - mean, dy = yy - mean;
  float vv = dx * dx + dy * dy;
#pragma unroll
  for (int d = 1; d < 64; d <<= 1) vv += __shfl_xor(vv, d);
  float rstd = rsqrtf(vv * (1.f / 128.f) + 1e-5f);
  float2 gg = *(const float2*)(g + (lane << 1));
  float2 bb = *(const float2*)(b + (lane << 1));
  float ox = dx * rstd * gg.x + bb.x;
  float oy = dy * rstd * gg.y + bb.y;
  *(float2*)(aggB + off) = make_float2(ox, oy);
  *(unsigned*)(h2b + off) = (unsigned)f2bf(ox) | ((unsigned)f2bf(oy) << 16);
}

// out_bf16 = LN(x + y)
__global__ void ln_residual(const float* __restrict__ x, const float* __restrict__ y,
                            const float* __restrict__ g, const float* __restrict__ b,
                            unsigned short* out)
{
  int n = blockIdx.x * 4 + (threadIdx.x >> 6);
  if (n >= NN) return;
  int lane = threadIdx.x & 63;
  int off = n * NH + (lane << 1);
  float2 xv = *(const float2*)(x + off);
  float2 yv = *(const float2*)(y + off);
  float ax = xv.x + yv.x, ay = xv.y + yv.y;
  float s = ax + ay;
#pragma unroll
  for (int d = 1; d < 64; d <<= 1) s += __shfl_xor(s, d);
  float mean = s * (1.f / 128.f);
  float dx = ax - mean, dy = ay - mean;
  float vv = dx * dx + dy * dy;
#pragma unroll
  for (int d = 1; d < 64; d <<= 1) vv += __shfl_xor(vv, d);
  float rstd = rsqrtf(vv * (1.f / 128.f) + 1e-5f);
  float2 gg = *(const float2*)(g + (lane << 1));
  float2 bb = *(const float2*)(b + (lane << 1));
  float ox = dx * rstd * gg.x + bb.x;
  float oy = dy * rstd * gg.y + bb.y;
  *(unsigned*)(out + off) = (unsigned)f2bf(ox) | ((unsigned)f2bf(oy) << 16);
}

__global__ void head_kernel(const float* __restrict__ R, const float* __restrict__ W2,
                            const float* __restrict__ b2, float* out)
{
  int n = blockIdx.x * 256 + threadIdx.x;
  if (n >= NN) return;
  const float* rr = R + n * 64;
  float a0 = 0.f, a1 = 0.f;
#pragma unroll
  for (int k = 0; k < 64; ++k) {
    float v = rr[k];
    a0 = fmaf(v, W2[k], a0);
    a1 = fmaf(v, W2[64 + k], a1);
  }
  out[n * 2]     = a0 + b2[0];
  out[n * 2 + 1] = a1 + b2[1];
}

extern "C" void kernel_launch(void* const* d_in, const int* in_sizes, int n_in,
                              void* d_out, int out_size, void* d_ws, size_t ws_size,
                              hipStream_t stream)
{
  const float* x      = (const float*)d_in[0];
  const int*   ei     = (const int*)  d_in[1];
  const float* ts     = (const float*)d_in[2];
  const float* mem    = (const float*)d_in[3];
  const float* W_in   = (const float*)d_in[4];
  const float* b_in   = (const float*)d_in[5];
  const float* W_time = (const float*)d_in[6];
  const float* b_time = (const float*)d_in[7];
  const float* W_ih   = (const float*)d_in[8];
  const float* W_hh   = (const float*)d_in[9];
  const float* b_ih   = (const float*)d_in[10];
  const float* b_hh   = (const float*)d_in[11];
  const float* W_gr   = (const float*)d_in[12];
  const float* b_gr   = (const float*)d_in[13];
  const float* W_gh   = (const float*)d_in[14];
  const float* b_gh   = (const float*)d_in[15];
  const float* ln_pa_g= (const float*)d_in[16];
  const float* ln_pa_b= (const float*)d_in[17];
  const float* Wv     = (const float*)d_in[18];
  const float* bv     = (const float*)d_in[19];
  const float* Wo     = (const float*)d_in[20];
  const float* bo     = (const float*)d_in[21];
  const float* ln_at_g= (const float*)d_in[22];
  const float* ln_at_b= (const float*)d_in[23];
  const float* W1     = (const float*)d_in[24];
  const float* b1     = (const float*)d_in[25];
  const float* W2     = (const float*)d_in[26];
  const float* b2     = (const float*)d_in[27];

  const int* row = ei;
  const int* col = ei + NE;
  float* out_logits = (float*)d_out;
  float* out_mem    = (float*)d_out + NN * 2;

  float* ws = (float*)d_ws;
  // phase-aliased layout (offsets in floats), ~64.7M floats total
  unsigned short* hb  = (unsigned short*)(ws);               // [0, 6.4M)  bf16 h; later h2b
  float* P            = ws + 6400000;                        // [6.4M, 44.8M)
  unsigned short* xb  = (unsigned short*)(ws + 6400000);     // inside P, dead before P written
  int* hist1          = (int*)(ws + 16000000);               // inside P (edge-stat phase only)
  int* h2a            = (int*)(ws + 16100000);
  int* h2b_hist       = (int*)(ws + 16200000);
  unsigned short* memb= (unsigned short*)(ws + 44800000);    // [44.8M, 51.2M)
  float* Q            = ws + 51200000;                       // [51.2M, 64.0M)
  unsigned short* wb  = (unsigned short*)(ws + 64000000);    // [64.0M, 64.1M)
  float* nt           = ws + 64100000;
  float* dis_r        = ws + 64200000;
  float* dis_h        = ws + 64300000;
  int* cnt_all        = (int*)(ws + 64400000);
  int* cnt_rec        = (int*)(ws + 64500000);
  int* upd            = (int*)(ws + 64600000);
  int* scal           = (int*)(ws + 64700000);
  // post-GRU reuse of P/memb/Q regions:
  float* aggB  = ws + 6400000;    // -> h2 in-place
  float* aggC  = ws + 19200000;   // -> vtb later
  float* hlr   = ws + 32000000;   // -> att later
  float* hlh   = ws + 44800000;   // -> rb, relu1 later
  unsigned short* h2bb = hb;                                  // bf16 h2 @0
  unsigned short* vtb  = (unsigned short*)(ws + 19200000);
  float* att           = ws + 32000000;
  unsigned short* rb   = (unsigned short*)(ws + 44800000);
  float* relu1         = ws + 51200000;

  unsigned short* wb_in = wb;
  unsigned short* wb_ih = wb + 24576;
  unsigned short* wb_hh = wb + 73728;
  unsigned short* wb_gr = wb + 122880;
  unsigned short* wb_gh = wb + 139264;
  unsigned short* wb_v  = wb + 155648;
  unsigned short* wb_o  = wb + 172032;
  unsigned short* wb_1  = wb + 188416;

  hipMemsetAsync(nt,      0, NN * 4, stream);
  hipMemsetAsync(cnt_all, 0, NN * 4, stream);
  hipMemsetAsync(cnt_rec, 0, NN * 4, stream);
  hipMemsetAsync(upd,     0, NN * 4, stream);
  hipMemsetAsync(hist1,   0, 65536 * 4, stream);
  hipMemsetAsync(h2a,     0, 65536 * 4, stream);
  hipMemsetAsync(h2b_hist,0, 65536 * 4, stream);
  hipMemsetAsync(scal,    0, 16 * 4, stream);
  hipMemsetAsync(scal + 5,0x7f, 4, stream);

  const int eb  = (NE + 255) / 256;
  const int nb  = (NN + 255) / 256;
  const int nhb = (NNH + 255) / 256;
  dim3 blk(256);

  // edge statistics (uses hist buffers living inside the not-yet-written P)
  edge_pass1 <<<eb, 256, 0, stream>>>(row, col, ts, nt, upd, cnt_all, hist1);
  node_minmax<<<nb, 256, 0, stream>>>(nt, scal);
  scan_hist1 <<<1, 256, 0, stream>>>(hist1, scal);
  edge_hist2 <<<eb, 256, 0, stream>>>(ts, scal, h2a, h2b_hist);
  scan_hist2 <<<1, 256, 0, stream>>>(h2a, h2b_hist, scal);
  edge_cntrec<<<eb, 256, 0, stream>>>(col, ts, scal, cnt_rec);
  node_dis   <<<nb, 256, 0, stream>>>(cnt_all, cnt_rec, dis_r, dis_h);

  // bf16 conversions
  conv_w  <<<768, 256, 0, stream>>>(W_in, W_ih, W_hh, W_gr, W_gh, Wv, Wo, W1, wb);
  conv_x  <<<75000, 256, 0, stream>>>(x, xb);
  conv_mem<<<50000, 256, 0, stream>>>(mem, memb);

  auto gg = [](int M) { return dim3((unsigned)((M + 127) / 128), (NN + 127) / 128); };

  // h (bf16 only) = relu(x@W_in.T + b_in + nt_norm*W_time + b_time) + mem
  mgemm<EPI_H, false, true><<<gg(128), blk, 0, stream>>>(xb, 192, wb_in, 192,
      nullptr, 0, hb, NH, 192, 128, b_in, b_time, W_time, nt, mem, scal);
  // P = h@W_ih.T + b_ih  [NN,384]
  mgemm<EPI_PLAIN, true, false><<<gg(384), blk, 0, stream>>>(hb, NH, wb_ih, NH,
      P, 384, nullptr, 0, 128, 384, b_ih, nullptr, nullptr, nullptr, nullptr, nullptr);
  // P[:, :256] += mem@W_hh[:256].T + b_hh[:256]
  mgemm<EPI_ACC, true, false><<<gg(256), blk, 0, stream>>>(memb, NH, wb_hh, NH,
      P, 384, nullptr, 0, 128, 256, b_hh, nullptr, nullptr, nullptr, nullptr, nullptr);
  // Q = mem@W_hh[256:].T + b_hh[256:]
  mgemm<EPI_PLAIN, true, false><<<gg(128), blk, 0, stream>>>(memb, NH, wb_hh + 256 * NH, NH,
      Q, NH, nullptr, 0, 128, 128, b_hh + 256, nullptr, nullptr, nullptr, nullptr, nullptr);
  gru_kernel<<<nhb, 256, 0, stream>>>(P, Q, mem, upd, out_mem);

  // GCN projections (P/Q regions now free)
  hipMemsetAsync(aggB, 0, (size_t)NNH * 4, stream);
  hipMemsetAsync(aggC, 0, (size_t)NNH * 4, stream);
  mgemm<EPI_PLAIN, true, false><<<gg(128), blk, 0, stream>>>(hb, NH, wb_gr, NH,
      hlr, NH, nullptr, 0, 128, 128, nullptr, nullptr, nullptr, nullptr, nullptr, nullptr);
  mgemm<EPI_PLAIN, true, false><<<gg(128), blk, 0, stream>>>(hb, NH, wb_gh, NH,
      hlh, NH, nullptr, 0, 128, 128, nullptr, nullptr, nullptr, nullptr, nullptr, nullptr);
  scatter_edges<<<(NE + 3) / 4, 256, 0, stream>>>(row, col, ts, scal, dis_r, dis_h,
      hlr, hlh, aggB, aggC);
  combine_pa<<<(NN + 3) / 4, 256, 0, stream>>>(aggB, aggC, hlr, hlh, dis_r, dis_h,
      b_gr, b_gh, ln_pa_g, ln_pa_b, h2bb);

  // attention (query path cancels)
  mgemm<EPI_PLAIN, false, true><<<gg(128), blk, 0, stream>>>(h2bb, NH, wb_v, NH,
      nullptr, 0, vtb, NH, 128, 128, bv, nullptr, nullptr, nullptr, nullptr, nullptr);
  mgemm<EPI_PLAIN, true, false><<<gg(128), blk, 0, stream>>>(vtb, NH, wb_o, NH,
      att, NH, nullptr, 0, 128, 128, bo, nullptr, nullptr, nullptr, nullptr, nullptr);
  ln_residual<<<(NN + 3) / 4, 256, 0, stream>>>(aggB, att, ln_at_g, ln_at_b, rb);

  // classifier
  mgemm<EPI_RELU, true, false><<<gg(64), blk, 0, stream>>>(rb, NH, wb_1, NH,
      relu1, 64, nullptr, 0, 128, 64, b1, nullptr, nullptr, nullptr, nullptr, nullptr);
  head_kernel<<<nb, 256, 0, stream>>>(relu1, W2, b2, out_logits);

  (void)in_sizes; (void)n_in; (void)out_size; (void)ws_size;
}

// Round 4
// 1388.090 us; speedup vs baseline: 1.9786x; 1.2853x over previous
//
#include <hip/hip_runtime.h>

#define NN 100000
#define NE 600000
#define NF 166
#define NH 128
#define NNH 12800000

enum { EPI_PLAIN = 0, EPI_ACC = 1, EPI_RELU = 2, EPI_H = 3 };

typedef short bf16x8 __attribute__((ext_vector_type(8)));
typedef float f32x16 __attribute__((ext_vector_type(16)));

__device__ __forceinline__ unsigned short f2bf(float f) {
  unsigned u = __float_as_uint(f);
  u += 0x7fffu + ((u >> 16) & 1u);
  return (unsigned short)(u >> 16);
}

// ---------------- MFMA GEMM: C[n,m] = epi(sum_k A[n,k]*W[m,k]) -------------
template<int EPI, bool WF32, bool WB16>
__launch_bounds__(256)
__global__ void mgemm(const unsigned short* __restrict__ A, int lda,
                      const unsigned short* __restrict__ W, int ldw,
                      float* C, int ldc,
                      unsigned short* Cb, int ldcb,
                      int K, int M,
                      const float* __restrict__ bias,
                      const float* __restrict__ b2v,
                      const float* __restrict__ wtv,
                      const float* __restrict__ nt,
                      const float* __restrict__ mem,
                      const int* __restrict__ scal)
{
  __shared__ unsigned short As[128 * 64];
  __shared__ unsigned short Bs[128 * 64];
  const int tid = threadIdx.x;
  const int wave = tid >> 6, lane = tid & 63;
  const int row0 = blockIdx.y * 128, col0 = blockIdx.x * 128;
  const int hi = lane >> 5, l5 = lane & 31, l3 = lane & 7;
  f32x16 acc[4] = {};

  for (int k0 = 0; k0 < K; k0 += 64) {
    __syncthreads();
#pragma unroll
    for (int q = 0; q < 4; ++q) {
      int id = q * 256 + tid;
      int r = id >> 3, cch = id & 7;
      int slot8 = ((cch ^ (r & 7)) << 3);
      int gr = row0 + r; if (gr > NN - 1) gr = NN - 1;
      *(int4*)&As[r * 64 + slot8] = *(const int4*)(A + (size_t)gr * lda + k0 + cch * 8);
      int gm = col0 + r; if (gm > M - 1) gm = M - 1;
      *(int4*)&Bs[r * 64 + slot8] = *(const int4*)(W + (size_t)gm * ldw + k0 + cch * 8);
    }
    __syncthreads();
#pragma unroll
    for (int s = 0; s < 4; ++s) {
      int slot8 = (((s * 2 + hi) ^ l3) << 3);
      bf16x8 a = *(const bf16x8*)&As[(wave * 32 + l5) * 64 + slot8];
#pragma unroll
      for (int t = 0; t < 4; ++t) {
        bf16x8 b = *(const bf16x8*)&Bs[(t * 32 + l5) * 64 + slot8];
        acc[t] = __builtin_amdgcn_mfma_f32_32x32x16_bf16(a, b, acc[t], 0, 0, 0);
      }
    }
  }

  float tmin = 0.f, tmax = 0.f;
  if (EPI == EPI_H) { tmin = __int_as_float(scal[5]); tmax = __int_as_float(scal[6]); }
#pragma unroll
  for (int rg = 0; rg < 16; ++rg) {
    int lr = (rg & 3) + 8 * (rg >> 2) + 4 * hi;
    int grow = row0 + wave * 32 + lr;
    if (grow >= NN) continue;
    float ntn = 0.f;
    if (EPI == EPI_H) {
      ntn = nt[grow];
      if (tmax > tmin) ntn = (ntn - tmin) / (tmax - tmin + 1e-8f);
    }
#pragma unroll
    for (int t = 0; t < 4; ++t) {
      int gcol = col0 + t * 32 + l5;
      if (gcol >= M) continue;
      float v = acc[t][rg];
      if (bias) v += bias[gcol];
      if (EPI == EPI_RELU) v = fmaxf(v, 0.f);
      if (EPI == EPI_H) {
        v += ntn * wtv[gcol] + b2v[gcol];
        v = fmaxf(v, 0.f);
        v += mem[(size_t)grow * NH + gcol];
      }
      if (EPI == EPI_ACC) v += C[(size_t)grow * ldc + gcol];
      if (WF32) C[(size_t)grow * ldc + gcol] = v;
      if (WB16) Cb[(size_t)grow * ldcb + gcol] = f2bf(v);
    }
  }
}

// ---------------- pre-convert kernels --------------------------------------
__global__ void conv_x(const float* __restrict__ x, unsigned short* __restrict__ xb)
{
  int i = blockIdx.x * 256 + threadIdx.x;
  if (i >= NN * 192) return;
  int n = i / 192, c = i - n * 192;
  xb[i] = (c < NF) ? f2bf(x[n * NF + c]) : (unsigned short)0;
}

__global__ void conv_mem(const float* __restrict__ m, unsigned short* __restrict__ mb)
{
  int i = blockIdx.x * 256 + threadIdx.x;
  if (i >= NNH) return;
  mb[i] = f2bf(m[i]);
}

__global__ void conv_w(const float* __restrict__ Wi, const float* __restrict__ Wih,
                       const float* __restrict__ Whh, const float* __restrict__ Wgr,
                       const float* __restrict__ Wgh, const float* __restrict__ Wv,
                       const float* __restrict__ Wo, const float* __restrict__ W1,
                       unsigned short* __restrict__ wb)
{
  int i = blockIdx.x * 256 + threadIdx.x;
  if (i >= 196608) return;
  float v;
  if (i < 24576)       { int r = i / 192, c = i - r * 192; v = (c < NF) ? Wi[r * NF + c] : 0.f; }
  else if (i < 73728)  v = Wih[i - 24576];
  else if (i < 122880) v = Whh[i - 73728];
  else if (i < 139264) v = Wgr[i - 122880];
  else if (i < 155648) v = Wgh[i - 139264];
  else if (i < 172032) v = Wv[i - 155648];
  else if (i < 188416) v = Wo[i - 172032];
  else                 v = W1[i - 188416];
  wb[i] = f2bf(v);
}

// ---------------- edge statistics ------------------------------------------
__global__ void edge_pass1(const int* __restrict__ row, const int* __restrict__ col,
                           const float* __restrict__ ts,
                           float* nt, int* upd, int* cnt_all, int* hist1)
{
  int e = blockIdx.x * 256 + threadIdx.x;
  if (e >= NE) return;
  int r = row[e], c = col[e];
  float t = ts[e];
  atomicMax((int*)(nt + c), __float_as_int(t));
  upd[r] = 1; upd[c] = 1;
  atomicAdd(cnt_all + c, 1);
  atomicAdd(hist1 + (int)(__float_as_uint(t) >> 16), 1);
}

__global__ void node_minmax(const float* __restrict__ nt, int* scal)
{
  int i = blockIdx.x * 256 + threadIdx.x;
  float v = (i < NN) ? nt[i] : nt[0];
  float vmin = v, vmax = v;
#pragma unroll
  for (int d = 1; d < 64; d <<= 1) {
    vmin = fminf(vmin, __shfl_xor(vmin, d));
    vmax = fmaxf(vmax, __shfl_xor(vmax, d));
  }
  __shared__ float smin[4], smax[4];
  int lane = threadIdx.x & 63, w = threadIdx.x >> 6;
  if (lane == 0) { smin[w] = vmin; smax[w] = vmax; }
  __syncthreads();
  if (threadIdx.x == 0) {
    float a = fminf(fminf(smin[0], smin[1]), fminf(smin[2], smin[3]));
    float b = fmaxf(fmaxf(smax[0], smax[1]), fmaxf(smax[2], smax[3]));
    atomicMin(scal + 5, __float_as_int(a));
    atomicMax(scal + 6, __float_as_int(b));
  }
}

__global__ void scan_hist1(const int* __restrict__ hist, int* scal)
{
  const int K1 = 299999, K2 = 300000;
  __shared__ int sums[256];
  __shared__ int pre[257];
  int t = threadIdx.x;
  int s = 0;
  for (int i = 0; i < 256; ++i) s += hist[t * 256 + i];
  sums[t] = s;
  __syncthreads();
  if (t == 0) { int run = 0; for (int i = 0; i < 256; ++i) { pre[i] = run; run += sums[i]; } pre[256] = run; }
  __syncthreads();
  int base = pre[t], nexts = base + sums[t];
  if (K1 >= base && K1 < nexts) {
    int run = base;
    for (int i = 0; i < 256; ++i) {
      int cv = hist[t * 256 + i];
      if (K1 < run + cv) { scal[0] = t * 256 + i; scal[1] = run; break; }
      run += cv;
    }
  }
  if (K2 >= base && K2 < nexts) {
    int run = base;
    for (int i = 0; i < 256; ++i) {
      int cv = hist[t * 256 + i];
      if (K2 < run + cv) { scal[2] = t * 256 + i; scal[3] = run; break; }
      run += cv;
    }
  }
}

__global__ void edge_hist2(const float* __restrict__ ts, const int* __restrict__ scal,
                           int* h2a, int* h2b)
{
  int e = blockIdx.x * 256 + threadIdx.x;
  if (e >= NE) return;
  unsigned u = __float_as_uint(ts[e]);
  int hb = (int)(u >> 16);
  if (hb == scal[0]) atomicAdd(h2a + (u & 0xffff), 1);
  if (hb == scal[2]) atomicAdd(h2b + (u & 0xffff), 1);
}

__global__ void scan_hist2(const int* __restrict__ ha, const int* __restrict__ hb,
                           int* scal)
{
  __shared__ int sums[256];
  __shared__ int pre[257];
  __shared__ unsigned res[2];
  int t = threadIdx.x;
  for (int which = 0; which < 2; ++which) {
    const int* h = which ? hb : ha;
    int rank = which ? (300000 - scal[3]) : (299999 - scal[1]);
    int s = 0;
    for (int i = 0; i < 256; ++i) s += h[t * 256 + i];
    sums[t] = s;
    __syncthreads();
    if (t == 0) { int run = 0; for (int i = 0; i < 256; ++i) { pre[i] = run; run += sums[i]; } pre[256] = run; }
    __syncthreads();
    int base = pre[t], nexts = base + sums[t];
    if (rank >= base && rank < nexts) {
      int run = base;
      for (int i = 0; i < 256; ++i) {
        int cv = h[t * 256 + i];
        if (rank < run + cv) { res[which] = (unsigned)(t * 256 + i); break; }
        run += cv;
      }
    }
    __syncthreads();
  }
  if (t == 0) {
    unsigned v1 = ((unsigned)scal[0] << 16) | res[0];
    unsigned v2 = ((unsigned)scal[2] << 16) | res[1];
    ((float*)scal)[4] = 0.5f * (__uint_as_float(v1) + __uint_as_float(v2));
  }
}

// ---------------- CSR build ------------------------------------------------
__global__ void csr_scan1(const int* __restrict__ cnt, int* loc, int* bsum)
{
  __shared__ int s[256];
  int t = threadIdx.x;
  int i = blockIdx.x * 256 + t;
  int v = (i < NN) ? cnt[i] : 0;
  s[t] = v;
  __syncthreads();
  for (int d = 1; d < 256; d <<= 1) {
    int add = (t >= d) ? s[t - d] : 0;
    __syncthreads();
    s[t] += add;
    __syncthreads();
  }
  if (i < NN) loc[i] = s[t] - v;
  if (t == 255) bsum[blockIdx.x] = s[255];
}

__global__ void csr_scan2(int* bsum, int nb)
{
  if (threadIdx.x == 0) {
    int run = 0;
    for (int i = 0; i < nb; ++i) { int v = bsum[i]; bsum[i] = run; run += v; }
  }
}

__global__ void csr_scan3(const int* __restrict__ loc, const int* __restrict__ bsum,
                          int* off, int* fillpos)
{
  int i = blockIdx.x * 256 + threadIdx.x;
  if (i < NN) {
    int o = loc[i] + bsum[i >> 8];
    off[i] = o;
    fillpos[i] = o;
  }
  if (i == 0) off[NN] = NE;
}

__global__ void csr_fill(const int* __restrict__ row, const int* __restrict__ col,
                         const float* __restrict__ ts, const int* __restrict__ scal,
                         int* fillpos, int* elist, int* cnt_rec)
{
  int e = blockIdx.x * 256 + threadIdx.x;
  if (e >= NE) return;
  int c = col[e], r = row[e];
  int rec = (ts[e] >= __int_as_float(scal[4])) ? 1 : 0;
  if (rec) atomicAdd(cnt_rec + c, 1);
  int slot = atomicAdd(fillpos + c, 1);
  elist[slot] = r | (rec << 31);
}

__global__ void node_dis(const int* __restrict__ cnt_all, const int* __restrict__ cnt_rec,
                         float* dr, float* dh)
{
  int n = blockIdx.x * 256 + threadIdx.x;
  if (n >= NN) return;
  int ca = cnt_all[n], cr = cnt_rec[n];
  dr[n] = rsqrtf((float)cr + 1.f);
  dh[n] = rsqrtf((float)(ca - cr) + 1.f);
}

// ---------------- GRU ------------------------------------------------------
__global__ void gru_kernel(const float* __restrict__ P, const float* __restrict__ Q,
                           const float* __restrict__ mem, const int* __restrict__ upd,
                           float* out)
{
  int idx = blockIdx.x * 256 + threadIdx.x;
  if (idx >= NNH) return;
  int n = idx >> 7, m = idx & 127;
  float mv = mem[idx];
  float o = mv;
  if (upd[n]) {
    int base = n * 384;
    float r = 1.f / (1.f + expf(-P[base + m]));
    float z = 1.f / (1.f + expf(-P[base + 128 + m]));
    float c = tanhf(P[base + 256 + m] + r * Q[idx]);
    o = (1.f - z) * c + z * mv;
  }
  out[idx] = o;
}

// ---------------- fused CSR gather + self-loop + softmax + LN --------------
// hl2: [NN, 256] fp32, cols 0:128 = RECENT proj (W_gr), 128:256 = HISTORY proj (W_gh).
// c0=1 means recent edge -> column offset 0; c0=0 (history) -> offset 128.
__global__ void gather_combine(const int* __restrict__ off, const int* __restrict__ elist,
                               const float* __restrict__ dis_r, const float* __restrict__ dis_h,
                               const float* __restrict__ hl2,
                               const float* __restrict__ bgr, const float* __restrict__ bgh,
                               const float* __restrict__ g, const float* __restrict__ b,
                               float* h2f, unsigned short* h2b)
{
  int n = blockIdx.x * 4 + (threadIdx.x >> 6);
  if (n >= NN) return;
  int lane = threadIdx.x & 63;
  int o0 = off[n], o1 = off[n + 1];
  float dnr = dis_r[n], dnh = dis_h[n];
  float arx = 0.f, ary = 0.f, ahx = 0.f, ahy = 0.f;
  int j = o0;
  for (; j + 1 < o1; j += 2) {
    int p0 = elist[j], p1 = elist[j + 1];
    int r0 = p0 & 0x7fffffff, r1 = p1 & 0x7fffffff;
    int c0 = ((unsigned)p0) >> 31, c1 = ((unsigned)p1) >> 31;
    float d0 = c0 ? dis_r[r0] : dis_h[r0];
    float d1 = c1 ? dis_r[r1] : dis_h[r1];
    const float2 v0 = *(const float2*)(hl2 + (size_t)r0 * 256 + ((c0 ^ 1) << 7) + (lane << 1));
    const float2 v1 = *(const float2*)(hl2 + (size_t)r1 * 256 + ((c1 ^ 1) << 7) + (lane << 1));
    float k0 = d0 * (c0 ? dnr : dnh);
    float k1 = d1 * (c1 ? dnr : dnh);
    if (c0) { arx = fmaf(k0, v0.x, arx); ary = fmaf(k0, v0.y, ary); }
    else    { ahx = fmaf(k0, v0.x, ahx); ahy = fmaf(k0, v0.y, ahy); }
    if (c1) { arx = fmaf(k1, v1.x, arx); ary = fmaf(k1, v1.y, ary); }
    else    { ahx = fmaf(k1, v1.x, ahx); ahy = fmaf(k1, v1.y, ahy); }
  }
  if (j < o1) {
    int p0 = elist[j];
    int r0 = p0 & 0x7fffffff;
    int c0 = ((unsigned)p0) >> 31;
    float d0 = c0 ? dis_r[r0] : dis_h[r0];
    const float2 v0 = *(const float2*)(hl2 + (size_t)r0 * 256 + ((c0 ^ 1) << 7) + (lane << 1));
    float k0 = d0 * (c0 ? dnr : dnh);
    if (c0) { arx = fmaf(k0, v0.x, arx); ary = fmaf(k0, v0.y, ary); }
    else    { ahx = fmaf(k0, v0.x, ahx); ahy = fmaf(k0, v0.y, ahy); }
  }
  // self-loop + bias
  const float2 lr = *(const float2*)(hl2 + (size_t)n * 256 + (lane << 1));
  const float2 lh = *(const float2*)(hl2 + (size_t)n * 256 + 128 + (lane << 1));
  float2 br = *(const float2*)(bgr + (lane << 1));
  float2 bh = *(const float2*)(bgh + (lane << 1));
  float rx = arx + lr.x * dnr * dnr + br.x;
  float ry = ary + lr.y * dnr * dnr + br.y;
  float hx = ahx + lh.x * dnh * dnh + bh.x;
  float hy = ahy + lh.y * dnh * dnh + bh.y;
  // path softmax over per-path means
  float sa = rx + ry, sc = hx + hy;
#pragma unroll
  for (int d = 1; d < 64; d <<= 1) { sa += __shfl_xor(sa, d); sc += __shfl_xor(sc, d); }
  float m0 = sa * (1.f / 128.f), m1 = sc * (1.f / 128.f);
  float mx = fmaxf(m0, m1);
  float e0 = expf(m0 - mx), e1 = expf(m1 - mx);
  float inv = 1.f / (e0 + e1);
  float w0 = e0 * inv, w1 = e1 * inv;
  float yx = w0 * rx + w1 * hx;
  float yy = w0 * ry + w1 * hy;
  // LayerNorm
  float s = yx + yy;
#pragma unroll
  for (int d = 1; d < 64; d <<= 1) s += __shfl_xor(s, d);
  float mean = s * (1.f / 128.f);
  float dx = yx - mean, dy = yy - mean;
  float vv = dx * dx + dy * dy;
#pragma unroll
  for (int d = 1; d < 64; d <<= 1) vv += __shfl_xor(vv, d);
  float rstd = rsqrtf(vv * (1.f / 128.f) + 1e-5f);
  float2 gg = *(const float2*)(g + (lane << 1));
  float2 bb = *(const float2*)(b + (lane << 1));
  float ox = dx * rstd * gg.x + bb.x;
  float oy = dy * rstd * gg.y + bb.y;
  int offo = n * NH + (lane << 1);
  *(float2*)(h2f + offo) = make_float2(ox, oy);
  *(unsigned*)(h2b + offo) = (unsigned)f2bf(ox) | ((unsigned)f2bf(oy) << 16);
}

// out_bf16 = LN(x + y)
__global__ void ln_residual(const float* __restrict__ x, const float* __restrict__ y,
                            const float* __restrict__ g, const float* __restrict__ b,
                            unsigned short* out)
{
  int n = blockIdx.x * 4 + (threadIdx.x >> 6);
  if (n >= NN) return;
  int lane = threadIdx.x & 63;
  int off = n * NH + (lane << 1);
  float2 xv = *(const float2*)(x + off);
  float2 yv = *(const float2*)(y + off);
  float ax = xv.x + yv.x, ay = xv.y + yv.y;
  float s = ax + ay;
#pragma unroll
  for (int d = 1; d < 64; d <<= 1) s += __shfl_xor(s, d);
  float mean = s * (1.f / 128.f);
  float dx = ax - mean, dy = ay - mean;
  float vv = dx * dx + dy * dy;
#pragma unroll
  for (int d = 1; d < 64; d <<= 1) vv += __shfl_xor(vv, d);
  float rstd = rsqrtf(vv * (1.f / 128.f) + 1e-5f);
  float2 gg = *(const float2*)(g + (lane << 1));
  float2 bb = *(const float2*)(b + (lane << 1));
  float ox = dx * rstd * gg.x + bb.x;
  float oy = dy * rstd * gg.y + bb.y;
  *(unsigned*)(out + off) = (unsigned)f2bf(ox) | ((unsigned)f2bf(oy) << 16);
}

__global__ void head_kernel(const float* __restrict__ R, const float* __restrict__ W2,
                            const float* __restrict__ b2, float* out)
{
  int n = blockIdx.x * 256 + threadIdx.x;
  if (n >= NN) return;
  const float* rr = R + n * 64;
  float a0 = 0.f, a1 = 0.f;
#pragma unroll
  for (int k = 0; k < 64; ++k) {
    float v = rr[k];
    a0 = fmaf(v, W2[k], a0);
    a1 = fmaf(v, W2[64 + k], a1);
  }
  out[n * 2]     = a0 + b2[0];
  out[n * 2 + 1] = a1 + b2[1];
}

extern "C" void kernel_launch(void* const* d_in, const int* in_sizes, int n_in,
                              void* d_out, int out_size, void* d_ws, size_t ws_size,
                              hipStream_t stream)
{
  const float* x      = (const float*)d_in[0];
  const int*   ei     = (const int*)  d_in[1];
  const float* ts     = (const float*)d_in[2];
  const float* mem    = (const float*)d_in[3];
  const float* W_in   = (const float*)d_in[4];
  const float* b_in   = (const float*)d_in[5];
  const float* W_time = (const float*)d_in[6];
  const float* b_time = (const float*)d_in[7];
  const float* W_ih   = (const float*)d_in[8];
  const float* W_hh   = (const float*)d_in[9];
  const float* b_ih   = (const float*)d_in[10];
  const float* b_hh   = (const float*)d_in[11];
  const float* W_gr   = (const float*)d_in[12];
  const float* b_gr   = (const float*)d_in[13];
  const float* W_gh   = (const float*)d_in[14];
  const float* b_gh   = (const float*)d_in[15];
  const float* ln_pa_g= (const float*)d_in[16];
  const float* ln_pa_b= (const float*)d_in[17];
  const float* Wv     = (const float*)d_in[18];
  const float* bv     = (const float*)d_in[19];
  const float* Wo     = (const float*)d_in[20];
  const float* bo     = (const float*)d_in[21];
  const float* ln_at_g= (const float*)d_in[22];
  const float* ln_at_b= (const float*)d_in[23];
  const float* W1     = (const float*)d_in[24];
  const float* b1     = (const float*)d_in[25];
  const float* W2     = (const float*)d_in[26];
  const float* b2     = (const float*)d_in[27];

  const int* row = ei;
  const int* col = ei + NE;
  float* out_logits = (float*)d_out;
  float* out_mem    = (float*)d_out + NN * 2;

  float* ws = (float*)d_ws;
  unsigned short* hb  = (unsigned short*)(ws);               // bf16 h; later bf16 h2
  float* P            = ws + 6400000;                        // [6.4M, 44.8M) GRU preacts
  unsigned short* xb  = (unsigned short*)(ws + 6400000);     // dead before P written
  int* hist1          = (int*)(ws + 16000000);               // edge-stat phase only
  int* h2a            = (int*)(ws + 16100000);
  int* h2b_hist       = (int*)(ws + 16200000);
  unsigned short* memb= (unsigned short*)(ws + 44800000);
  float* Q            = ws + 51200000;
  unsigned short* wb  = (unsigned short*)(ws + 64000000);
  float* nt           = ws + 64100000;
  float* dis_r        = ws + 64200000;
  float* dis_h        = ws + 64300000;
  int* cnt_all        = (int*)(ws + 64400000);
  int* cnt_rec        = (int*)(ws + 64500000);
  int* upd            = (int*)(ws + 64600000);
  int* scal           = (int*)(ws + 64700000);
  // post-GRU phase aliases:
  float* h2f   = ws + 6400000;
  int* off     = (int*)(ws + 19200000);
  int* fillpos = (int*)(ws + 19350000);
  int* loc     = (int*)(ws + 19500000);
  int* bsum    = (int*)(ws + 19700000);
  int* elist   = (int*)(ws + 19800000);
  float* hl2   = ws + 32000000;                     // [NN,256] fp32 GCN projections
  unsigned short* h2bb = hb;
  unsigned short* vtb  = (unsigned short*)(ws + 19200000);
  float* att           = ws + 32000000;
  unsigned short* rb   = (unsigned short*)(ws + 44800000);
  float* relu1         = ws + 51200000;

  unsigned short* wb_in = wb;
  unsigned short* wb_ih = wb + 24576;
  unsigned short* wb_hh = wb + 73728;
  unsigned short* wb_gr = wb + 122880;   // [256,128] = W_gr ++ W_gh contiguous
  unsigned short* wb_v  = wb + 155648;
  unsigned short* wb_o  = wb + 172032;
  unsigned short* wb_1  = wb + 188416;

  hipMemsetAsync(nt,      0, NN * 4, stream);
  hipMemsetAsync(cnt_all, 0, NN * 4, stream);
  hipMemsetAsync(cnt_rec, 0, NN * 4, stream);
  hipMemsetAsync(upd,     0, NN * 4, stream);
  hipMemsetAsync(hist1,   0, 65536 * 4, stream);
  hipMemsetAsync(h2a,     0, 65536 * 4, stream);
  hipMemsetAsync(h2b_hist,0, 65536 * 4, stream);
  hipMemsetAsync(scal,    0, 16 * 4, stream);
  hipMemsetAsync(scal + 5,0x7f, 4, stream);

  const int eb  = (NE + 255) / 256;
  const int nb  = (NN + 255) / 256;
  const int nhb = (NNH + 255) / 256;
  dim3 blk(256);

  // edge statistics
  edge_pass1 <<<eb, 256, 0, stream>>>(row, col, ts, nt, upd, cnt_all, hist1);
  node_minmax<<<nb, 256, 0, stream>>>(nt, scal);
  scan_hist1 <<<1, 256, 0, stream>>>(hist1, scal);
  edge_hist2 <<<eb, 256, 0, stream>>>(ts, scal, h2a, h2b_hist);
  scan_hist2 <<<1, 256, 0, stream>>>(h2a, h2b_hist, scal);

  // bf16 conversions
  conv_w  <<<768, 256, 0, stream>>>(W_in, W_ih, W_hh, W_gr, W_gh, Wv, Wo, W1, wb);
  conv_x  <<<75000, 256, 0, stream>>>(x, xb);
  conv_mem<<<50000, 256, 0, stream>>>(mem, memb);

  auto gg = [](int M) { return dim3((unsigned)((M + 127) / 128), (NN + 127) / 128); };

  // h = relu(x@W_in.T + b_in + nt_norm*W_time + b_time) + mem   (bf16 out)
  mgemm<EPI_H, false, true><<<gg(128), blk, 0, stream>>>(xb, 192, wb_in, 192,
      nullptr, 0, hb, NH, 192, 128, b_in, b_time, W_time, nt, mem, scal);
  // GRU preacts
  mgemm<EPI_PLAIN, true, false><<<gg(384), blk, 0, stream>>>(hb, NH, wb_ih, NH,
      P, 384, nullptr, 0, 128, 384, b_ih, nullptr, nullptr, nullptr, nullptr, nullptr);
  mgemm<EPI_ACC, true, false><<<gg(256), blk, 0, stream>>>(memb, NH, wb_hh, NH,
      P, 384, nullptr, 0, 128, 256, b_hh, nullptr, nullptr, nullptr, nullptr, nullptr);
  mgemm<EPI_PLAIN, true, false><<<gg(128), blk, 0, stream>>>(memb, NH, wb_hh + 256 * NH, NH,
      Q, NH, nullptr, 0, 128, 128, b_hh + 256, nullptr, nullptr, nullptr, nullptr, nullptr);
  gru_kernel<<<nhb, 256, 0, stream>>>(P, Q, mem, upd, out_mem);

  // CSR build (P/Q regions now free)
  csr_scan1<<<nb, 256, 0, stream>>>(cnt_all, loc, bsum);
  csr_scan2<<<1, 64, 0, stream>>>(bsum, nb);
  csr_scan3<<<nb, 256, 0, stream>>>(loc, bsum, off, fillpos);
  csr_fill <<<eb, 256, 0, stream>>>(row, col, ts, scal, fillpos, elist, cnt_rec);
  node_dis <<<nb, 256, 0, stream>>>(cnt_all, cnt_rec, dis_r, dis_h);

  // both GCN projections in one GEMM: hl2 = h @ [W_gr; W_gh].T  [NN,256]
  mgemm<EPI_PLAIN, true, false><<<gg(256), blk, 0, stream>>>(hb, NH, wb_gr, NH,
      hl2, 256, nullptr, 0, 128, 256, nullptr, nullptr, nullptr, nullptr, nullptr, nullptr);

  // fused gather + self-loop + path softmax + LN
  gather_combine<<<(NN + 3) / 4, 256, 0, stream>>>(off, elist, dis_r, dis_h, hl2,
      b_gr, b_gh, ln_pa_g, ln_pa_b, h2f, h2bb);

  // attention (query path cancels)
  mgemm<EPI_PLAIN, false, true><<<gg(128), blk, 0, stream>>>(h2bb, NH, wb_v, NH,
      nullptr, 0, vtb, NH, 128, 128, bv, nullptr, nullptr, nullptr, nullptr, nullptr);
  mgemm<EPI_PLAIN, true, false><<<gg(128), blk, 0, stream>>>(vtb, NH, wb_o, NH,
      att, NH, nullptr, 0, 128, 128, bo, nullptr, nullptr, nullptr, nullptr, nullptr);
  ln_residual<<<(NN + 3) / 4, 256, 0, stream>>>(h2f, att, ln_at_g, ln_at_b, rb);

  // classifier
  mgemm<EPI_RELU, true, false><<<gg(64), blk, 0, stream>>>(rb, NH, wb_1, NH,
      relu1, 64, nullptr, 0, 128, 64, b1, nullptr, nullptr, nullptr, nullptr, nullptr);
  head_kernel<<<nb, 256, 0, stream>>>(relu1, W2, b2, out_logits);

  (void)in_sizes; (void)n_in; (void)out_size; (void)ws_size;
}

// Round 6
// 1093.355 us; speedup vs baseline: 2.5120x; 1.2696x over previous
//
#include <hip/hip_runtime.h>

#define NN 100000
#define NE 600000
#define NF 166
#define NH 128
#define NNH 12800000

enum { EPI_PLAIN = 0, EPI_ACC = 1, EPI_RELU = 2, EPI_H = 3 };

typedef short bf16x8 __attribute__((ext_vector_type(8)));
typedef float f32x16 __attribute__((ext_vector_type(16)));

__device__ __forceinline__ unsigned short f2bf(float f) {
  unsigned u = __float_as_uint(f);
  u += 0x7fffu + ((u >> 16) & 1u);
  return (unsigned short)(u >> 16);
}

// ---------------- MFMA GEMM: C[n,m] = epi(sum_k A[n,k]*W[m,k]) -------------
template<int EPI, bool WF32, bool WB16>
__launch_bounds__(256)
__global__ void mgemm(const unsigned short* __restrict__ A, int lda,
                      const unsigned short* __restrict__ W, int ldw,
                      float* C, int ldc,
                      unsigned short* Cb, int ldcb,
                      int K, int M,
                      const float* __restrict__ bias,
                      const float* __restrict__ b2v,
                      const float* __restrict__ wtv,
                      const float* __restrict__ nt,
                      const float* __restrict__ mem,
                      const int* __restrict__ scal)
{
  __shared__ unsigned short As[128 * 64];
  __shared__ unsigned short Bs[128 * 64];
  const int tid = threadIdx.x;
  const int wave = tid >> 6, lane = tid & 63;
  const int row0 = blockIdx.y * 128, col0 = blockIdx.x * 128;
  const int hi = lane >> 5, l5 = lane & 31, l3 = lane & 7;
  f32x16 acc[4] = {};

  for (int k0 = 0; k0 < K; k0 += 64) {
    __syncthreads();
#pragma unroll
    for (int q = 0; q < 4; ++q) {
      int id = q * 256 + tid;
      int r = id >> 3, cch = id & 7;
      int slot8 = ((cch ^ (r & 7)) << 3);
      int gr = row0 + r; if (gr > NN - 1) gr = NN - 1;
      *(int4*)&As[r * 64 + slot8] = *(const int4*)(A + (size_t)gr * lda + k0 + cch * 8);
      int gm = col0 + r; if (gm > M - 1) gm = M - 1;
      *(int4*)&Bs[r * 64 + slot8] = *(const int4*)(W + (size_t)gm * ldw + k0 + cch * 8);
    }
    __syncthreads();
#pragma unroll
    for (int s = 0; s < 4; ++s) {
      int slot8 = (((s * 2 + hi) ^ l3) << 3);
      bf16x8 a = *(const bf16x8*)&As[(wave * 32 + l5) * 64 + slot8];
#pragma unroll
      for (int t = 0; t < 4; ++t) {
        bf16x8 b = *(const bf16x8*)&Bs[(t * 32 + l5) * 64 + slot8];
        acc[t] = __builtin_amdgcn_mfma_f32_32x32x16_bf16(a, b, acc[t], 0, 0, 0);
      }
    }
  }

  float tmin = 0.f, tmax = 0.f;
  if (EPI == EPI_H) { tmin = __int_as_float(scal[5]); tmax = __int_as_float(scal[6]); }
#pragma unroll
  for (int rg = 0; rg < 16; ++rg) {
    int lr = (rg & 3) + 8 * (rg >> 2) + 4 * hi;
    int grow = row0 + wave * 32 + lr;
    if (grow >= NN) continue;
    float ntn = 0.f;
    if (EPI == EPI_H) {
      ntn = nt[grow];
      if (tmax > tmin) ntn = (ntn - tmin) / (tmax - tmin + 1e-8f);
    }
#pragma unroll
    for (int t = 0; t < 4; ++t) {
      int gcol = col0 + t * 32 + l5;
      if (gcol >= M) continue;
      float v = acc[t][rg];
      if (bias) v += bias[gcol];
      if (EPI == EPI_RELU) v = fmaxf(v, 0.f);
      if (EPI == EPI_H) {
        v += ntn * wtv[gcol] + b2v[gcol];
        v = fmaxf(v, 0.f);
        v += mem[(size_t)grow * NH + gcol];
      }
      if (EPI == EPI_ACC) v += C[(size_t)grow * ldc + gcol];
      if (WF32) C[(size_t)grow * ldc + gcol] = v;
      if (WB16) Cb[(size_t)grow * ldcb + gcol] = f2bf(v);
    }
  }
}

// ---------------- pre-convert kernels --------------------------------------
__global__ void conv_x(const float* __restrict__ x, unsigned short* __restrict__ xb)
{
  int i = blockIdx.x * 256 + threadIdx.x;
  if (i >= NN * 192) return;
  int n = i / 192, c = i - n * 192;
  xb[i] = (c < NF) ? f2bf(x[n * NF + c]) : (unsigned short)0;
}

__global__ void conv_mem(const float* __restrict__ m, unsigned short* __restrict__ mb)
{
  int i = blockIdx.x * 256 + threadIdx.x;
  if (i >= NNH) return;
  mb[i] = f2bf(m[i]);
}

__global__ void conv_w(const float* __restrict__ Wi, const float* __restrict__ Wih,
                       const float* __restrict__ Whh, const float* __restrict__ Wgr,
                       const float* __restrict__ Wgh, const float* __restrict__ Wv,
                       const float* __restrict__ Wo, const float* __restrict__ W1,
                       unsigned short* __restrict__ wb)
{
  int i = blockIdx.x * 256 + threadIdx.x;
  if (i >= 196608) return;
  float v;
  if (i < 24576)       { int r = i / 192, c = i - r * 192; v = (c < NF) ? Wi[r * NF + c] : 0.f; }
  else if (i < 73728)  v = Wih[i - 24576];
  else if (i < 122880) v = Whh[i - 73728];
  else if (i < 139264) v = Wgr[i - 122880];
  else if (i < 155648) v = Wgh[i - 139264];
  else if (i < 172032) v = Wv[i - 155648];
  else if (i < 188416) v = Wo[i - 172032];
  else                 v = W1[i - 188416];
  wb[i] = f2bf(v);
}

// ---------------- edge statistics ------------------------------------------
// Value-uniform binning: ts ~ U[0,1) -> bin = floor(t*65536), ~9 edges/bin.
// Monotone in t, so order-statistic selection over bins is exact.
__device__ __forceinline__ int ts_bin(float t) {
  int b = (int)(t * 65536.0f);
  return b > 65535 ? 65535 : (b < 0 ? 0 : b);
}

__global__ void edge_pass1(const int* __restrict__ row, const int* __restrict__ col,
                           const float* __restrict__ ts,
                           float* nt, int* upd, int* cnt_all, int* hist1)
{
  int e = blockIdx.x * 256 + threadIdx.x;
  if (e >= NE) return;
  int r = row[e], c = col[e];
  float t = ts[e];
  atomicMax((int*)(nt + c), __float_as_int(t));
  upd[r] = 1; upd[c] = 1;
  atomicAdd(cnt_all + c, 1);
  atomicAdd(hist1 + ts_bin(t), 1);
}

__global__ void node_minmax(const float* __restrict__ nt, int* scal)
{
  int i = blockIdx.x * 256 + threadIdx.x;
  float v = (i < NN) ? nt[i] : nt[0];
  float vmin = v, vmax = v;
#pragma unroll
  for (int d = 1; d < 64; d <<= 1) {
    vmin = fminf(vmin, __shfl_xor(vmin, d));
    vmax = fmaxf(vmax, __shfl_xor(vmax, d));
  }
  __shared__ float smin[4], smax[4];
  int lane = threadIdx.x & 63, w = threadIdx.x >> 6;
  if (lane == 0) { smin[w] = vmin; smax[w] = vmax; }
  __syncthreads();
  if (threadIdx.x == 0) {
    float a = fminf(fminf(smin[0], smin[1]), fminf(smin[2], smin[3]));
    float b = fmaxf(fmaxf(smax[0], smax[1]), fmaxf(smax[2], smax[3]));
    atomicMin(scal + 5, __float_as_int(a));
    atomicMax(scal + 6, __float_as_int(b));
  }
}

// find bins of order statistics K1=299999, K2=300000 (0-based) in hist1
__global__ void scan_hist1(const int* __restrict__ hist, int* scal)
{
  const int K1 = 299999, K2 = 300000;
  __shared__ int sums[256];
  __shared__ int pre[257];
  int t = threadIdx.x;
  int s = 0;
  for (int i = 0; i < 256; ++i) s += hist[t * 256 + i];
  sums[t] = s;
  __syncthreads();
  if (t == 0) { int run = 0; for (int i = 0; i < 256; ++i) { pre[i] = run; run += sums[i]; } pre[256] = run; }
  __syncthreads();
  int base = pre[t], nexts = base + sums[t];
  if (K1 >= base && K1 < nexts) {
    int run = base;
    for (int i = 0; i < 256; ++i) {
      int cv = hist[t * 256 + i];
      if (K1 < run + cv) { scal[0] = t * 256 + i; scal[1] = run; break; }
      run += cv;
    }
  }
  if (K2 >= base && K2 < nexts) {
    int run = base;
    for (int i = 0; i < 256; ++i) {
      int cv = hist[t * 256 + i];
      if (K2 < run + cv) { scal[2] = t * 256 + i; scal[3] = run; break; }
      run += cv;
    }
  }
}

#define CAND_CAP 4096
__global__ void collect_cand(const float* __restrict__ ts, const int* __restrict__ scal,
                             float* cand1, float* cand2, int* ccnt)
{
  int e = blockIdx.x * 256 + threadIdx.x;
  if (e >= NE) return;
  float t = ts[e];
  int b = ts_bin(t);
  if (b == scal[0]) {
    int s = atomicAdd(ccnt + 0, 1);
    if (s < CAND_CAP) cand1[s] = t;
  }
  if (b == scal[2]) {
    int s = atomicAdd(ccnt + 1, 1);
    if (s < CAND_CAP) cand2[s] = t;
  }
}

// exact rank-select within candidate bins; med = mean of the two order stats
__global__ void select_med(const float* __restrict__ c1, const float* __restrict__ c2,
                           const int* __restrict__ ccnt, int* scal)
{
  __shared__ float res[2];
  for (int which = 0; which < 2; ++which) {
    const float* c = which ? c2 : c1;
    int m = ccnt[which]; if (m > CAND_CAP) m = CAND_CAP;
    int rank = which ? (300000 - scal[3]) : (299999 - scal[1]);
    for (int i = threadIdx.x; i < m; i += 256) {
      float v = c[i];
      int less = 0, eq = 0;
      for (int j = 0; j < m; ++j) { float w = c[j]; less += (w < v); eq += (w == v); }
      if (less <= rank && rank < less + eq) res[which] = v;
    }
  }
  __syncthreads();
  if (threadIdx.x == 0)
    ((float*)scal)[4] = 0.5f * (res[0] + res[1]);
}

// ---------------- CSR build ------------------------------------------------
__global__ void csr_scan1(const int* __restrict__ cnt, int* loc, int* bsum)
{
  __shared__ int s[256];
  int t = threadIdx.x;
  int i = blockIdx.x * 256 + t;
  int v = (i < NN) ? cnt[i] : 0;
  s[t] = v;
  __syncthreads();
  for (int d = 1; d < 256; d <<= 1) {
    int add = (t >= d) ? s[t - d] : 0;
    __syncthreads();
    s[t] += add;
    __syncthreads();
  }
  if (i < NN) loc[i] = s[t] - v;
  if (t == 255) bsum[blockIdx.x] = s[255];
}

__global__ void csr_scan2(int* bsum, int nb)
{
  if (threadIdx.x == 0) {
    int run = 0;
    for (int i = 0; i < nb; ++i) { int v = bsum[i]; bsum[i] = run; run += v; }
  }
}

__global__ void csr_scan3(const int* __restrict__ loc, const int* __restrict__ bsum,
                          int* off, int* fillpos)
{
  int i = blockIdx.x * 256 + threadIdx.x;
  if (i < NN) {
    int o = loc[i] + bsum[i >> 8];
    off[i] = o;
    fillpos[i] = o;
  }
  if (i == 0) off[NN] = NE;
}

__global__ void csr_fill(const int* __restrict__ row, const int* __restrict__ col,
                         const float* __restrict__ ts, const int* __restrict__ scal,
                         int* fillpos, int* elist, int* cnt_rec)
{
  int e = blockIdx.x * 256 + threadIdx.x;
  if (e >= NE) return;
  int c = col[e], r = row[e];
  int rec = (ts[e] >= __int_as_float(scal[4])) ? 1 : 0;
  if (rec) atomicAdd(cnt_rec + c, 1);
  int slot = atomicAdd(fillpos + c, 1);
  elist[slot] = r | (rec << 31);
}

__global__ void node_dis(const int* __restrict__ cnt_all, const int* __restrict__ cnt_rec,
                         float* dr, float* dh)
{
  int n = blockIdx.x * 256 + threadIdx.x;
  if (n >= NN) return;
  int ca = cnt_all[n], cr = cnt_rec[n];
  dr[n] = rsqrtf((float)cr + 1.f);
  dh[n] = rsqrtf((float)(ca - cr) + 1.f);
}

// ---------------- GRU ------------------------------------------------------
__global__ void gru_kernel(const float* __restrict__ P, const float* __restrict__ Q,
                           const float* __restrict__ mem, const int* __restrict__ upd,
                           float* out)
{
  int idx = blockIdx.x * 256 + threadIdx.x;
  if (idx >= NNH) return;
  int n = idx >> 7, m = idx & 127;
  float mv = mem[idx];
  float o = mv;
  if (upd[n]) {
    int base = n * 384;
    float r = 1.f / (1.f + expf(-P[base + m]));
    float z = 1.f / (1.f + expf(-P[base + 128 + m]));
    float c = tanhf(P[base + 256 + m] + r * Q[idx]);
    o = (1.f - z) * c + z * mv;
  }
  out[idx] = o;
}

// ---------------- fused CSR gather + self-loop + softmax + LN --------------
// hl2: [NN, 256] fp32, cols 0:128 = RECENT proj (W_gr), 128:256 = HISTORY (W_gh).
// c0=1 (recent) -> column offset 0; c0=0 (history) -> offset 128.
__global__ void gather_combine(const int* __restrict__ off, const int* __restrict__ elist,
                               const float* __restrict__ dis_r, const float* __restrict__ dis_h,
                               const float* __restrict__ hl2,
                               const float* __restrict__ bgr, const float* __restrict__ bgh,
                               const float* __restrict__ g, const float* __restrict__ b,
                               float* h2f, unsigned short* h2b)
{
  int n = blockIdx.x * 4 + (threadIdx.x >> 6);
  if (n >= NN) return;
  int lane = threadIdx.x & 63;
  int o0 = off[n], o1 = off[n + 1];
  float dnr = dis_r[n], dnh = dis_h[n];
  float arx = 0.f, ary = 0.f, ahx = 0.f, ahy = 0.f;
  int j = o0;
  for (; j + 1 < o1; j += 2) {
    int p0 = elist[j], p1 = elist[j + 1];
    int r0 = p0 & 0x7fffffff, r1 = p1 & 0x7fffffff;
    int c0 = ((unsigned)p0) >> 31, c1 = ((unsigned)p1) >> 31;
    float d0 = c0 ? dis_r[r0] : dis_h[r0];
    float d1 = c1 ? dis_r[r1] : dis_h[r1];
    const float2 v0 = *(const float2*)(hl2 + (size_t)r0 * 256 + ((c0 ^ 1) << 7) + (lane << 1));
    const float2 v1 = *(const float2*)(hl2 + (size_t)r1 * 256 + ((c1 ^ 1) << 7) + (lane << 1));
    float k0 = d0 * (c0 ? dnr : dnh);
    float k1 = d1 * (c1 ? dnr : dnh);
    if (c0) { arx = fmaf(k0, v0.x, arx); ary = fmaf(k0, v0.y, ary); }
    else    { ahx = fmaf(k0, v0.x, ahx); ahy = fmaf(k0, v0.y, ahy); }
    if (c1) { arx = fmaf(k1, v1.x, arx); ary = fmaf(k1, v1.y, ary); }
    else    { ahx = fmaf(k1, v1.x, ahx); ahy = fmaf(k1, v1.y, ahy); }
  }
  if (j < o1) {
    int p0 = elist[j];
    int r0 = p0 & 0x7fffffff;
    int c0 = ((unsigned)p0) >> 31;
    float d0 = c0 ? dis_r[r0] : dis_h[r0];
    const float2 v0 = *(const float2*)(hl2 + (size_t)r0 * 256 + ((c0 ^ 1) << 7) + (lane << 1));
    float k0 = d0 * (c0 ? dnr : dnh);
    if (c0) { arx = fmaf(k0, v0.x, arx); ary = fmaf(k0, v0.y, ary); }
    else    { ahx = fmaf(k0, v0.x, ahx); ahy = fmaf(k0, v0.y, ahy); }
  }
  // self-loop + bias
  const float2 lr = *(const float2*)(hl2 + (size_t)n * 256 + (lane << 1));
  const float2 lh = *(const float2*)(hl2 + (size_t)n * 256 + 128 + (lane << 1));
  float2 br = *(const float2*)(bgr + (lane << 1));
  float2 bh = *(const float2*)(bgh + (lane << 1));
  float rx = arx + lr.x * dnr * dnr + br.x;
  float ry = ary + lr.y * dnr * dnr + br.y;
  float hx = ahx + lh.x * dnh * dnh + bh.x;
  float hy = ahy + lh.y * dnh * dnh + bh.y;
  // path softmax over per-path means
  float sa = rx + ry, sc = hx + hy;
#pragma unroll
  for (int d = 1; d < 64; d <<= 1) { sa += __shfl_xor(sa, d); sc += __shfl_xor(sc, d); }
  float m0 = sa * (1.f / 128.f), m1 = sc * (1.f / 128.f);
  float mx = fmaxf(m0, m1);
  float e0 = expf(m0 - mx), e1 = expf(m1 - mx);
  float inv = 1.f / (e0 + e1);
  float w0 = e0 * inv, w1 = e1 * inv;
  float yx = w0 * rx + w1 * hx;
  float yy = w0 * ry + w1 * hy;
  // LayerNorm
  float s = yx + yy;
#pragma unroll
  for (int d = 1; d < 64; d <<= 1) s += __shfl_xor(s, d);
  float mean = s * (1.f / 128.f);
  float dx = yx - mean, dy = yy - mean;
  float vv = dx * dx + dy * dy;
#pragma unroll
  for (int d = 1; d < 64; d <<= 1) vv += __shfl_xor(vv, d);
  float rstd = rsqrtf(vv * (1.f / 128.f) + 1e-5f);
  float2 gg = *(const float2*)(g + (lane << 1));
  float2 bb = *(const float2*)(b + (lane << 1));
  float ox = dx * rstd * gg.x + bb.x;
  float oy = dy * rstd * gg.y + bb.y;
  int offo = n * NH + (lane << 1);
  *(float2*)(h2f + offo) = make_float2(ox, oy);
  *(unsigned*)(h2b + offo) = (unsigned)f2bf(ox) | ((unsigned)f2bf(oy) << 16);
}

// out_bf16 = LN(x + y)
__global__ void ln_residual(const float* __restrict__ x, const float* __restrict__ y,
                            const float* __restrict__ g, const float* __restrict__ b,
                            unsigned short* out)
{
  int n = blockIdx.x * 4 + (threadIdx.x >> 6);
  if (n >= NN) return;
  int lane = threadIdx.x & 63;
  int off = n * NH + (lane << 1);
  float2 xv = *(const float2*)(x + off);
  float2 yv = *(const float2*)(y + off);
  float ax = xv.x + yv.x, ay = xv.y + yv.y;
  float s = ax + ay;
#pragma unroll
  for (int d = 1; d < 64; d <<= 1) s += __shfl_xor(s, d);
  float mean = s * (1.f / 128.f);
  float dx = ax - mean, dy = ay - mean;
  float vv = dx * dx + dy * dy;
#pragma unroll
  for (int d = 1; d < 64; d <<= 1) vv += __shfl_xor(vv, d);
  float rstd = rsqrtf(vv * (1.f / 128.f) + 1e-5f);
  float2 gg = *(const float2*)(g + (lane << 1));
  float2 bb = *(const float2*)(b + (lane << 1));
  float ox = dx * rstd * gg.x + bb.x;
  float oy = dy * rstd * gg.y + bb.y;
  *(unsigned*)(out + off) = (unsigned)f2bf(ox) | ((unsigned)f2bf(oy) << 16);
}

__global__ void head_kernel(const float* __restrict__ R, const float* __restrict__ W2,
                            const float* __restrict__ b2, float* out)
{
  int n = blockIdx.x * 256 + threadIdx.x;
  if (n >= NN) return;
  const float* rr = R + n * 64;
  float a0 = 0.f, a1 = 0.f;
#pragma unroll
  for (int k = 0; k < 64; ++k) {
    float v = rr[k];
    a0 = fmaf(v, W2[k], a0);
    a1 = fmaf(v, W2[64 + k], a1);
  }
  out[n * 2]     = a0 + b2[0];
  out[n * 2 + 1] = a1 + b2[1];
}

extern "C" void kernel_launch(void* const* d_in, const int* in_sizes, int n_in,
                              void* d_out, int out_size, void* d_ws, size_t ws_size,
                              hipStream_t stream)
{
  const float* x      = (const float*)d_in[0];
  const int*   ei     = (const int*)  d_in[1];
  const float* ts     = (const float*)d_in[2];
  const float* mem    = (const float*)d_in[3];
  const float* W_in   = (const float*)d_in[4];
  const float* b_in   = (const float*)d_in[5];
  const float* W_time = (const float*)d_in[6];
  const float* b_time = (const float*)d_in[7];
  const float* W_ih   = (const float*)d_in[8];
  const float* W_hh   = (const float*)d_in[9];
  const float* b_ih   = (const float*)d_in[10];
  const float* b_hh   = (const float*)d_in[11];
  const float* W_gr   = (const float*)d_in[12];
  const float* b_gr   = (const float*)d_in[13];
  const float* W_gh   = (const float*)d_in[14];
  const float* b_gh   = (const float*)d_in[15];
  const float* ln_pa_g= (const float*)d_in[16];
  const float* ln_pa_b= (const float*)d_in[17];
  const float* Wv     = (const float*)d_in[18];
  const float* bv     = (const float*)d_in[19];
  const float* Wo     = (const float*)d_in[20];
  const float* bo     = (const float*)d_in[21];
  const float* ln_at_g= (const float*)d_in[22];
  const float* ln_at_b= (const float*)d_in[23];
  const float* W1     = (const float*)d_in[24];
  const float* b1     = (const float*)d_in[25];
  const float* W2     = (const float*)d_in[26];
  const float* b2     = (const float*)d_in[27];

  const int* row = ei;
  const int* col = ei + NE;
  float* out_logits = (float*)d_out;
  float* out_mem    = (float*)d_out + NN * 2;

  float* ws = (float*)d_ws;
  // ---- workspace layout (offsets in floats) — validated by round-4 pass ----
  unsigned short* hb  = (unsigned short*)(ws);               // [0, 6.4M) bf16 h; later bf16 h2
  float* P            = ws + 6400000;                        // [6.4M, 44.8M) GRU preacts
  unsigned short* xb  = (unsigned short*)(ws + 6400000);     // [6.4M, 16.0M) dead before P written
  int* hist1          = (int*)(ws + 16000000);               // edge-stat phase only
  unsigned short* memb= (unsigned short*)(ws + 44800000);    // [44.8M, 51.2M)
  float* Q            = ws + 51200000;                       // [51.2M, 64.0M)
  unsigned short* wb  = (unsigned short*)(ws + 64000000);    // [64.0M, 64.1M) — NEVER overlap!
  float* nt           = ws + 64100000;
  float* dis_r        = ws + 64200000;
  float* dis_h        = ws + 64300000;
  int* cnt_all        = (int*)(ws + 64400000);
  int* cnt_rec        = (int*)(ws + 64500000);
  int* upd            = (int*)(ws + 64600000);
  int* scal           = (int*)(ws + 64700000);
  float* cand1        = ws + 64710000;
  float* cand2        = ws + 64715000;
  int* ccnt           = (int*)(ws + 64720000);
  // post-GRU phase aliases (identical to round-4 passing layout):
  float* h2f   = ws + 6400000;                      // [6.4M, 19.2M)
  int* off     = (int*)(ws + 19200000);             // CSR offsets [NN+1]
  int* fillpos = (int*)(ws + 19350000);
  int* loc     = (int*)(ws + 19500000);
  int* bsum    = (int*)(ws + 19700000);
  int* elist   = (int*)(ws + 19800000);             // [19.8M, 20.4M)
  float* hl2   = ws + 32000000;                     // [32.0M, 57.6M) fp32 [NN,256]
  unsigned short* h2bb = hb;
  unsigned short* vtb  = (unsigned short*)(ws + 19200000);   // [19.2M, 25.6M) after gather
  float* att           = ws + 32000000;                      // [32.0M, 44.8M) after gather
  unsigned short* rb   = (unsigned short*)(ws + 44800000);   // [44.8M, 51.2M)
  float* relu1         = ws + 51200000;                      // [51.2M, 57.6M)

  unsigned short* wb_in = wb;
  unsigned short* wb_ih = wb + 24576;
  unsigned short* wb_hh = wb + 73728;
  unsigned short* wb_gr = wb + 122880;   // [256,128] = W_gr ++ W_gh contiguous
  unsigned short* wb_v  = wb + 155648;
  unsigned short* wb_o  = wb + 172032;
  unsigned short* wb_1  = wb + 188416;

  hipMemsetAsync(nt,      0, NN * 4, stream);
  hipMemsetAsync(cnt_all, 0, NN * 4, stream);
  hipMemsetAsync(cnt_rec, 0, NN * 4, stream);
  hipMemsetAsync(upd,     0, NN * 4, stream);
  hipMemsetAsync(hist1,   0, 65536 * 4, stream);
  hipMemsetAsync(scal,    0, 16 * 4, stream);
  hipMemsetAsync(scal + 5,0x7f, 4, stream);
  hipMemsetAsync(ccnt,    0, 8, stream);

  const int eb  = (NE + 255) / 256;
  const int nb  = (NN + 255) / 256;
  const int nhb = (NNH + 255) / 256;
  dim3 blk(256);

  // edge statistics (uniform value-binned median selection)
  edge_pass1  <<<eb, 256, 0, stream>>>(row, col, ts, nt, upd, cnt_all, hist1);
  node_minmax <<<nb, 256, 0, stream>>>(nt, scal);
  scan_hist1  <<<1, 256, 0, stream>>>(hist1, scal);
  collect_cand<<<eb, 256, 0, stream>>>(ts, scal, cand1, cand2, ccnt);
  select_med  <<<1, 256, 0, stream>>>(cand1, cand2, ccnt, scal);

  // bf16 conversions
  conv_w  <<<768, 256, 0, stream>>>(W_in, W_ih, W_hh, W_gr, W_gh, Wv, Wo, W1, wb);
  conv_x  <<<75000, 256, 0, stream>>>(x, xb);
  conv_mem<<<50000, 256, 0, stream>>>(mem, memb);

  auto gg = [](int M) { return dim3((unsigned)((M + 127) / 128), (NN + 127) / 128); };

  // h = relu(x@W_in.T + b_in + nt_norm*W_time + b_time) + mem   (bf16 out)
  mgemm<EPI_H, false, true><<<gg(128), blk, 0, stream>>>(xb, 192, wb_in, 192,
      nullptr, 0, hb, NH, 192, 128, b_in, b_time, W_time, nt, mem, scal);
  // GRU preacts
  mgemm<EPI_PLAIN, true, false><<<gg(384), blk, 0, stream>>>(hb, NH, wb_ih, NH,
      P, 384, nullptr, 0, 128, 384, b_ih, nullptr, nullptr, nullptr, nullptr, nullptr);
  mgemm<EPI_ACC, true, false><<<gg(256), blk, 0, stream>>>(memb, NH, wb_hh, NH,
      P, 384, nullptr, 0, 128, 256, b_hh, nullptr, nullptr, nullptr, nullptr, nullptr);
  mgemm<EPI_PLAIN, true, false><<<gg(128), blk, 0, stream>>>(memb, NH, wb_hh + 256 * NH, NH,
      Q, NH, nullptr, 0, 128, 128, b_hh + 256, nullptr, nullptr, nullptr, nullptr, nullptr);
  gru_kernel<<<nhb, 256, 0, stream>>>(P, Q, mem, upd, out_mem);

  // CSR build (P/Q regions now free)
  csr_scan1<<<nb, 256, 0, stream>>>(cnt_all, loc, bsum);
  csr_scan2<<<1, 64, 0, stream>>>(bsum, nb);
  csr_scan3<<<nb, 256, 0, stream>>>(loc, bsum, off, fillpos);
  csr_fill <<<eb, 256, 0, stream>>>(row, col, ts, scal, fillpos, elist, cnt_rec);
  node_dis <<<nb, 256, 0, stream>>>(cnt_all, cnt_rec, dis_r, dis_h);

  // both GCN projections in one GEMM: hl2 = h @ [W_gr; W_gh].T  [NN,256] fp32
  mgemm<EPI_PLAIN, true, false><<<gg(256), blk, 0, stream>>>(hb, NH, wb_gr, NH,
      hl2, 256, nullptr, 0, 128, 256, nullptr, nullptr, nullptr, nullptr, nullptr, nullptr);

  // fused gather + self-loop + path softmax + LN
  gather_combine<<<(NN + 3) / 4, 256, 0, stream>>>(off, elist, dis_r, dis_h, hl2,
      b_gr, b_gh, ln_pa_g, ln_pa_b, h2f, h2bb);

  // attention (query path cancels)
  mgemm<EPI_PLAIN, false, true><<<gg(128), blk, 0, stream>>>(h2bb, NH, wb_v, NH,
      nullptr, 0, vtb, NH, 128, 128, bv, nullptr, nullptr, nullptr, nullptr, nullptr);
  mgemm<EPI_PLAIN, true, false><<<gg(128), blk, 0, stream>>>(vtb, NH, wb_o, NH,
      att, NH, nullptr, 0, 128, 128, bo, nullptr, nullptr, nullptr, nullptr, nullptr);
  ln_residual<<<(NN + 3) / 4, 256, 0, stream>>>(h2f, att, ln_at_g, ln_at_b, rb);

  // classifier
  mgemm<EPI_RELU, true, false><<<gg(64), blk, 0, stream>>>(rb, NH, wb_1, NH,
      relu1, 64, nullptr, 0, 128, 64, b1, nullptr, nullptr, nullptr, nullptr, nullptr);
  head_kernel<<<nb, 256, 0, stream>>>(relu1, W2, b2, out_logits);

  (void)in_sizes; (void)n_in; (void)out_size; (void)ws_size;
}